// Round 3
// baseline (1789.808 us; speedup 1.0000x reference)
//
#include <hip/hip_runtime.h>
#include <hip/hip_cooperative_groups.h>

namespace cg = cooperative_groups;

// Problem constants (fixed by setup_inputs)
constexpr int NDA = 10000;   // target graph nodes
constexpr int NQ  = 64;      // query graph nodes
constexpr int CND = 1024;    // candidate set size
constexpr int DIN = 128;     // input feature dim
constexpr int D   = 256;     // hidden dim
constexpr int CAP = 96;      // max nnz per adjacency row (Poisson(20); P(>96) ~ 0)
constexpr int NB_BIG = ((NDA + 63) / 64) * (D / 64);   // 628 tiles for 10000x256 gemm
constexpr int NCHUNK = 16;
constexpr int GCHUNK = 640;  // 16*640 = 10240 >= NDA, guarded

#define LRELU(x) ((x) >= 0.f ? (x) : 0.01f * (x))

__device__ __forceinline__ float wave_red64(float v) {
#pragma unroll
    for (int o = 32; o; o >>= 1) v += __shfl_down(v, o);
    return v;
}

// ---------------------------------------------------------------------------
// Shared-memory union: one allocation (17.4 KB) reused by every stage body.
struct GemmSmem  { float As[32][68]; float Bs[32][68]; };
struct CrossSmem { float qs[D]; float cmw[256]; int sci[256]; float red[4]; float sqn; };
struct SpmmSmem  { int sc[CAP]; };
struct CsrSmem   { int scnt; };
struct EndSmem   { float se[D]; float scnt; };
struct FinalSmem { int sc[CAP]; float smask[CAP]; int sdiag; float r1[4], r2[4], r3[4]; };
struct GpSmem    { float SA[8][64]; float SB[8][64]; };
struct AttqSmem  { float red[4]; };
union SMem {
    GemmSmem g; CrossSmem c; SpmmSmem s; CsrSmem z;
    EndSmem e; FinalSmem f; GpSmem gp; AttqSmem a;
};

// ---------------------------------------------------------------------------
// GEMM body: C[M,N] = op(A)[M,K] @ B[K,N]. 64x64 tile, 256 threads, 4x4/thread.
// K-slab 32 (K % 32 == 0), register double-buffer prefetch. N == 256 assumed ok.
template <bool RELU_A, bool RELU_C>
__device__ __forceinline__ void gemm_body(GemmSmem& sm, int bx, int by,
                                          const float* __restrict__ A,
                                          const float* __restrict__ B,
                                          float* __restrict__ C,
                                          int M, int N, int K) {
    const int bm = bx * 64, bn = by * 64;
    const int tid = threadIdx.x;
    const int tx = tid & 15, ty = tid >> 4;
    const int lm = tid >> 2, lk = (tid & 3) * 8;   // A-tile: 64 rows x 32 k
    const int kb = tid >> 3, nb = (tid & 7) * 8;   // B-tile: 32 k x 64 cols
    const bool aValid = (bm + lm) < M;
    const float* aPtr = A + (size_t)(bm + lm) * K + lk;
    const float* bPtr = B + (size_t)kb * N + bn + nb;
    float4 ra0 = make_float4(0.f, 0.f, 0.f, 0.f), ra1 = ra0, rb0, rb1;
    if (aValid) { ra0 = *(const float4*)aPtr; ra1 = *(const float4*)(aPtr + 4); }
    rb0 = *(const float4*)bPtr;
    rb1 = *(const float4*)(bPtr + 4);
    float acc[4][4] = {};
    for (int k0 = 0; k0 < K; k0 += 32) {
        float4 wa0 = ra0, wa1 = ra1, wb0 = rb0, wb1 = rb1;
        if (RELU_A) {
            wa0.x = LRELU(wa0.x); wa0.y = LRELU(wa0.y); wa0.z = LRELU(wa0.z); wa0.w = LRELU(wa0.w);
            wa1.x = LRELU(wa1.x); wa1.y = LRELU(wa1.y); wa1.z = LRELU(wa1.z); wa1.w = LRELU(wa1.w);
        }
        sm.As[lk + 0][lm] = wa0.x; sm.As[lk + 1][lm] = wa0.y;
        sm.As[lk + 2][lm] = wa0.z; sm.As[lk + 3][lm] = wa0.w;
        sm.As[lk + 4][lm] = wa1.x; sm.As[lk + 5][lm] = wa1.y;
        sm.As[lk + 6][lm] = wa1.z; sm.As[lk + 7][lm] = wa1.w;
        *(float4*)&sm.Bs[kb][nb]     = wb0;
        *(float4*)&sm.Bs[kb][nb + 4] = wb1;
        __syncthreads();
        if (k0 + 32 < K) {   // prefetch next tiles; hides under the inner loop
            if (aValid) {
                ra0 = *(const float4*)(aPtr + k0 + 32);
                ra1 = *(const float4*)(aPtr + k0 + 36);
            }
            rb0 = *(const float4*)(bPtr + (size_t)(k0 + 32) * N);
            rb1 = *(const float4*)(bPtr + (size_t)(k0 + 32) * N + 4);
        }
#pragma unroll
        for (int kk = 0; kk < 32; kk++) {
            float av[4], bv[4];
#pragma unroll
            for (int i = 0; i < 4; i++) av[i] = sm.As[kk][ty * 4 + i];
#pragma unroll
            for (int j = 0; j < 4; j++) bv[j] = sm.Bs[kk][tx * 4 + j];
#pragma unroll
            for (int i = 0; i < 4; i++)
#pragma unroll
                for (int j = 0; j < 4; j++) acc[i][j] += av[i] * bv[j];
        }
        __syncthreads();
    }
#pragma unroll
    for (int i = 0; i < 4; i++) {
        int r = bm + ty * 4 + i;
        if (r < M) {
            float4 v = make_float4(acc[i][0], acc[i][1], acc[i][2], acc[i][3]);
            if (RELU_C) { v.x = LRELU(v.x); v.y = LRELU(v.y); v.z = LRELU(v.z); v.w = LRELU(v.w); }
            *(float4*)(C + (size_t)r * N + bn + tx * 4) = v;
        }
    }
}

// ---------------------------------------------------------------------------
__device__ __forceinline__ void csr_body(CsrSmem& sm, const float* __restrict__ adj,
                                         int* __restrict__ cols,
                                         int* __restrict__ rowcnt, int row) {
    if (threadIdx.x == 0) sm.scnt = 0;
    __syncthreads();
    const float4* rp = (const float4*)(adj + (size_t)row * NDA);
    for (int i = threadIdx.x; i < NDA / 4; i += 256) {
        float4 v = rp[i];
        if (v.x != 0.f) { int s = atomicAdd(&sm.scnt, 1); if (s < CAP) cols[row * CAP + s] = 4 * i; }
        if (v.y != 0.f) { int s = atomicAdd(&sm.scnt, 1); if (s < CAP) cols[row * CAP + s] = 4 * i + 1; }
        if (v.z != 0.f) { int s = atomicAdd(&sm.scnt, 1); if (s < CAP) cols[row * CAP + s] = 4 * i + 2; }
        if (v.w != 0.f) { int s = atomicAdd(&sm.scnt, 1); if (s < CAP) cols[row * CAP + s] = 4 * i + 3; }
    }
    __syncthreads();
    if (threadIdx.x == 0) rowcnt[row] = min(sm.scnt, CAP);
}

// ---------------------------------------------------------------------------
__device__ __forceinline__ void spmm_body(SpmmSmem& sm, const int* __restrict__ cols,
                                          const int* __restrict__ rowcnt,
                                          const float* __restrict__ X,
                                          float* __restrict__ out1,
                                          float* __restrict__ out2, int row) {
    int d = threadIdx.x;
    int cnt = rowcnt[row];
    if (d < cnt) sm.sc[d] = cols[row * CAP + d];
    __syncthreads();
    float a0 = 0.f, a1 = 0.f, a2 = 0.f, a3 = 0.f;
    int k = 0;
    for (; k + 4 <= cnt; k += 4) {
        a0 += X[(size_t)sm.sc[k + 0] * D + d];
        a1 += X[(size_t)sm.sc[k + 1] * D + d];
        a2 += X[(size_t)sm.sc[k + 2] * D + d];
        a3 += X[(size_t)sm.sc[k + 3] * D + d];
    }
    for (; k < cnt; k++) a0 += X[(size_t)sm.sc[k] * D + d];
    float v = LRELU(a0 + a1 + a2 + a3);
    out1[(size_t)row * D + d] = v;
    if (out2) out2[(size_t)row * D + d] = LRELU(v);
}

// ---------------------------------------------------------------------------
__device__ __forceinline__ void cross_body(CrossSmem& sm, const float* __restrict__ q,
                                           const float* __restrict__ da,
                                           const int* __restrict__ cand,
                                           float* __restrict__ hpart,
                                           int r, int qr) {
    int d = threadIdx.x;
    float qv = q[r * D + d];
    sm.qs[d] = qv;
    sm.sci[d] = cand[qr * 256 + d];
    float p = wave_red64(qv * qv);
    int w = d >> 6, lane = d & 63;
    if (lane == 0) sm.red[w] = p;
    __syncthreads();
    if (d == 0) sm.sqn = fmaxf(sqrtf(sm.red[0] + sm.red[1] + sm.red[2] + sm.red[3]), 1e-12f);
    __syncthreads();
    float qn = sm.sqn;
    {
        const float4* ap = (const float4*)(da + (size_t)sm.sci[d] * D);
        float dot = 0.f, sq = 0.f;
#pragma unroll 8
        for (int k = 0; k < D / 4; k++) {
            float4 v = ap[k];
            dot += sm.qs[4 * k] * v.x + sm.qs[4 * k + 1] * v.y + sm.qs[4 * k + 2] * v.z + sm.qs[4 * k + 3] * v.w;
            sq  += v.x * v.x + v.y * v.y + v.z * v.z + v.w * v.w;
        }
        sm.cmw[d] = dot / (qn * fmaxf(sqrtf(sq), 1e-12f));
    }
    __syncthreads();
    float a0 = 0.f, a1 = 0.f, a2 = 0.f, a3 = 0.f, a4 = 0.f, a5 = 0.f, a6 = 0.f, a7 = 0.f;
    for (int c = 0; c < 256; c += 8) {
        a0 += sm.cmw[c + 0] * da[(size_t)sm.sci[c + 0] * D + d];
        a1 += sm.cmw[c + 1] * da[(size_t)sm.sci[c + 1] * D + d];
        a2 += sm.cmw[c + 2] * da[(size_t)sm.sci[c + 2] * D + d];
        a3 += sm.cmw[c + 3] * da[(size_t)sm.sci[c + 3] * D + d];
        a4 += sm.cmw[c + 4] * da[(size_t)sm.sci[c + 4] * D + d];
        a5 += sm.cmw[c + 5] * da[(size_t)sm.sci[c + 5] * D + d];
        a6 += sm.cmw[c + 6] * da[(size_t)sm.sci[c + 6] * D + d];
        a7 += sm.cmw[c + 7] * da[(size_t)sm.sci[c + 7] * D + d];
    }
    hpart[((size_t)qr * NQ + r) * D + d] = ((a0 + a1) + (a2 + a3)) + ((a4 + a5) + (a6 + a7));
}

// ---------------------------------------------------------------------------
// att_q = lrelu(q + h / max(colnorm(h),1e-12)); two-pass over r to avoid a
// 64-entry register array (keeps fused-kernel VGPR count down).
__device__ __forceinline__ void attq_body(AttqSmem& sm, const float* __restrict__ q,
                                          const float* __restrict__ hpart,
                                          float* __restrict__ attq,
                                          float* __restrict__ emb) {
    int d = threadIdx.x;
    float ss = 0.f;
#pragma unroll 4
    for (int r = 0; r < NQ; r++) {
        float h = hpart[(size_t)r * D + d]
                + hpart[(size_t)(NQ + r) * D + d]
                + hpart[(size_t)(2 * NQ + r) * D + d]
                + hpart[(size_t)(3 * NQ + r) * D + d];
        ss += h * h;
    }
    float inv = 1.f / fmaxf(sqrtf(ss), 1e-12f);
    float es = 0.f;
#pragma unroll 4
    for (int r = 0; r < NQ; r++) {
        float h = hpart[(size_t)r * D + d]
                + hpart[(size_t)(NQ + r) * D + d]
                + hpart[(size_t)(2 * NQ + r) * D + d]
                + hpart[(size_t)(3 * NQ + r) * D + d];
        float v = q[r * D + d] + h * inv;
        v = LRELU(v);
        attq[r * D + d] = v;
        es += v;
    }
    if (emb) {
        float e = es * (1.f / (float)NQ);
        emb[d] = e;
        float p = wave_red64(e * e);
        int w = d >> 6, lane = d & 63;
        if (lane == 0) sm.red[w] = p;
        __syncthreads();
        if (d == 0) emb[D] = sqrtf(sm.red[0] + sm.red[1] + sm.red[2] + sm.red[3]);
    }
}

// ---------------------------------------------------------------------------
__device__ __forceinline__ void end_body(EndSmem& sm, const float* __restrict__ A,
                                         const float* __restrict__ emb,
                                         const float* __restrict__ thr_p,
                                         float* __restrict__ endv,
                                         float* __restrict__ m,
                                         float* __restrict__ cnt, int quad) {
    int d = threadIdx.x;
    sm.se[d] = emb[d];
    if (d == 0) sm.scnt = 0.f;
    __syncthreads();
    float embn = emb[D];
    float thr = *thr_p;
    int w = d >> 6, lane = d & 63;
    int row = quad * 4 + w;
    const float* ar = A + (size_t)row * D;
    float num = 0.f, sq = 0.f;
#pragma unroll
    for (int s = 0; s < 4; s++) {
        float v = ar[lane + 64 * s];
        num += v * sm.se[lane + 64 * s];
        sq += v * v;
    }
#pragma unroll
    for (int o = 32; o; o >>= 1) { num += __shfl_down(num, o); sq += __shfl_down(sq, o); }
    if (lane == 0) {
        float den = fmaxf(sqrtf(sq) * embn, 1e-8f);
        float e = num / den;
        endv[row] = e;
        float mv = e > thr ? 1.f : 0.f;
        m[row] = mv;
        if (mv != 0.f) atomicAdd(&sm.scnt, 1.f);
    }
    __syncthreads();
    if (d == 0 && sm.scnt != 0.f) atomicAdd(cnt, sm.scnt);
}

// ---------------------------------------------------------------------------
__device__ __forceinline__ void gpart_body(GpSmem& sm, const float* __restrict__ A,
                                           const float* __restrict__ m,
                                           float* __restrict__ Gp, int tile, int chunk) {
    int ti = tile >> 2, tj = tile & 3;
    int base = chunk * GCHUNK;
    int tid = threadIdx.x;
    int tx = tid & 15, ty = tid >> 4;
    float acc[4][4] = {};
    for (int g0 = 0; g0 < GCHUNK; g0 += 8) {
        for (int l = tid; l < 512; l += 256) {
            int rr = l >> 6, c = l & 63;
            int r = base + g0 + rr;
            float av = 0.f, bv = 0.f, mv = 0.f;
            if (r < NDA) {
                mv = m[r];
                av = A[(size_t)r * D + ti * 64 + c];
                bv = A[(size_t)r * D + tj * 64 + c];
            }
            sm.SA[rr][c] = av * mv;
            sm.SB[rr][c] = bv;
        }
        __syncthreads();
#pragma unroll
        for (int rr = 0; rr < 8; rr++) {
            float av[4], bv[4];
#pragma unroll
            for (int i = 0; i < 4; i++) av[i] = sm.SA[rr][ty * 4 + i];
#pragma unroll
            for (int j = 0; j < 4; j++) bv[j] = sm.SB[rr][tx * 4 + j];
#pragma unroll
            for (int i = 0; i < 4; i++)
#pragma unroll
                for (int j = 0; j < 4; j++) acc[i][j] += av[i] * bv[j];
        }
        __syncthreads();
    }
    float* gp = Gp + (size_t)chunk * D * D;
#pragma unroll
    for (int i = 0; i < 4; i++)
#pragma unroll
        for (int j = 0; j < 4; j++)
            gp[(ti * 64 + ty * 4 + i) * D + tj * 64 + tx * 4 + j] = acc[i][j];
}

// ---------------------------------------------------------------------------
__device__ __forceinline__ void final_body(FinalSmem& sm, const int* __restrict__ cols,
                                           const int* __restrict__ rowcnt,
                                           const float* __restrict__ m,
                                           const float* __restrict__ A,
                                           const float* __restrict__ H,
                                           double* __restrict__ total,
                                           double* __restrict__ tr, int i) {
    if (m[i] == 0.f) return;   // block-uniform
    int d = threadIdx.x;
    int cnt = rowcnt[i];
    if (d == 0) sm.sdiag = 0;
    if (d < cnt) {
        int j = cols[i * CAP + d];
        sm.sc[d] = j;
        sm.smask[d] = m[j];
        if (j == i) sm.sdiag = 1;
    }
    __syncthreads();
    float av = A[(size_t)i * D + d];
    float hv = H[(size_t)i * D + d];
    float sd = 0.f;
    for (int k = 0; k < cnt; k++)
        if (sm.smask[k] != 0.f) sd += A[(size_t)sm.sc[k] * D + d];
    float p1 = av * sd, p2 = av * hv, p3 = av * av;
#pragma unroll
    for (int o = 32; o; o >>= 1) {
        p1 += __shfl_down(p1, o);
        p2 += __shfl_down(p2, o);
        p3 += __shfl_down(p3, o);
    }
    int w = d >> 6, lane = d & 63;
    if (lane == 0) { sm.r1[w] = p1; sm.r2[w] = p2; sm.r3[w] = p3; }
    __syncthreads();
    if (d == 0) {
        float num  = sm.r1[0] + sm.r1[1] + sm.r1[2] + sm.r1[3];
        float den2 = sm.r2[0] + sm.r2[1] + sm.r2[2] + sm.r2[3];
        float self = sm.r3[0] + sm.r3[1] + sm.r3[2] + sm.r3[3];
        float denom = fmaxf(sqrtf(den2), 1e-12f);
        double inv = 1.0 / (double)denom;
        if (num != 0.f) atomicAdd(total, (double)num * inv);
        if (sm.sdiag) atomicAdd(tr, (double)self * inv);
    }
}

// ---------------------------------------------------------------------------
// Parameter block for the cooperative mega-kernel.
struct P {
    const float *adj, *Fda, *Qadj, *Fq;
    const int* cand;
    const float* thr;
    const float *W1da, *W1q, *W2da, *W2q;
    float *o_end, *o_attda2, *o_attq2, *o_sc;
    float *bufA, *bufB, *bufC;
    int *cols, *rowcnt;
    float *m, *Gb, *Gp;
    float* cnt; double *tot, *tr;
    float *xq, *q1, *aq1, *q2, *hpart, *emb;
};

// The entire pipeline in ONE dispatch; cg::grid.sync() between stages.
__global__ __launch_bounds__(256) void mega(P p) {
    cg::grid_group grid = cg::this_grid();
    __shared__ SMem sm;
    const int nb = gridDim.x;
    const int b0 = blockIdx.x;
    // S0: zero accumulators; [X1 gemm | Xq gemm | CSR build]
    if (b0 == 0 && threadIdx.x == 0) { *p.cnt = 0.f; *p.tot = 0.0; *p.tr = 0.0; }
    for (int it = b0; it < NB_BIG + 4 + NDA; it += nb) {
        if (it < NB_BIG) gemm_body<false, false>(sm.g, it >> 2, it & 3, p.Fda, p.W1da, p.bufA, NDA, D, DIN);
        else if (it < NB_BIG + 4) gemm_body<false, false>(sm.g, 0, it - NB_BIG, p.Fq, p.W1q, p.xq, NQ, D, DIN);
        else csr_body(sm.z, p.adj, p.cols, p.rowcnt, it - (NB_BIG + 4));
        __syncthreads();
    }
    grid.sync();
    // S1: [q1 gemm | spmm da1]
    for (int it = b0; it < 4 + NDA; it += nb) {
        if (it < 4) gemm_body<false, true>(sm.g, 0, it, p.Qadj, p.xq, p.q1, NQ, D, NQ);
        else spmm_body(sm.s, p.cols, p.rowcnt, p.bufA, p.bufB, nullptr, it - 4);
        __syncthreads();
    }
    grid.sync();
    // S2: [cross1 | Y2 = lrelu(da1)@W2da]
    for (int it = b0; it < 256 + NB_BIG; it += nb) {
        if (it < 256) cross_body(sm.c, p.q1, p.bufB, p.cand, p.hpart, it >> 2, it & 3);
        else { int t = it - 256; gemm_body<true, false>(sm.g, t >> 2, t & 3, p.bufB, p.W2da, p.bufA, NDA, D, D); }
        __syncthreads();
    }
    grid.sync();
    // S3: [attq1 -> aq1 | spmm da2 rows [0,5000)]
    for (int it = b0; it < 1 + 5000; it += nb) {
        if (it == 0) attq_body(sm.a, p.q1, p.hpart, p.aq1, nullptr);
        else spmm_body(sm.s, p.cols, p.rowcnt, p.bufA, p.bufC, p.o_attda2, it - 1);
        __syncthreads();
    }
    grid.sync();
    // S4: [Zq = aq1@W2q | spmm da2 rows [5000,10000)]
    for (int it = b0; it < 4 + 5000; it += nb) {
        if (it < 4) gemm_body<false, false>(sm.g, 0, it, p.aq1, p.W2q, p.xq, NQ, D, D);
        else spmm_body(sm.s, p.cols, p.rowcnt, p.bufA, p.bufC, p.o_attda2, 5000 + (it - 4));
        __syncthreads();
    }
    grid.sync();
    // S5: q2 = lrelu(Qadj@Zq)
    for (int it = b0; it < 4; it += nb) {
        gemm_body<false, true>(sm.g, 0, it, p.Qadj, p.xq, p.q2, NQ, D, NQ);
        __syncthreads();
    }
    grid.sync();
    // S6: cross2
    for (int it = b0; it < 256; it += nb) {
        cross_body(sm.c, p.q2, p.bufC, p.cand, p.hpart, it >> 2, it & 3);
        __syncthreads();
    }
    grid.sync();
    // S7: attq2 + emb
    for (int it = b0; it < 1; it += nb) {
        attq_body(sm.a, p.q2, p.hpart, p.o_attq2, p.emb);
        __syncthreads();
    }
    grid.sync();
    // S8: end scores + mask
    for (int it = b0; it < NDA / 4; it += nb) {
        end_body(sm.e, p.o_attda2, p.emb, p.thr, p.o_end, p.m, p.cnt, it);
        __syncthreads();
    }
    grid.sync();
    // S9: G partials (no atomics)
    for (int it = b0; it < 16 * NCHUNK; it += nb) {
        gpart_body(sm.gp, p.o_attda2, p.m, p.Gp, it & 15, it >> 4);
        __syncthreads();
    }
    grid.sync();
    // S10: reduce partials -> G
    for (int it = b0; it < (D * D) / 256; it += nb) {
        int idx = it * 256 + (int)threadIdx.x;
        float s = 0.f;
#pragma unroll
        for (int c2 = 0; c2 < NCHUNK; c2++) s += p.Gp[(size_t)c2 * D * D + idx];
        p.Gb[idx] = s;
    }
    grid.sync();
    // S11: H = att_da2 @ G
    for (int it = b0; it < NB_BIG; it += nb) {
        gemm_body<false, false>(sm.g, it >> 2, it & 3, p.o_attda2, p.Gb, p.bufB, NDA, D, D);
        __syncthreads();
    }
    grid.sync();
    // S12: final masked-row reduction
    for (int it = b0; it < NDA; it += nb) {
        final_body(sm.f, p.cols, p.rowcnt, p.m, p.o_attda2, p.bufB, p.tot, p.tr, it);
        __syncthreads();
    }
    grid.sync();
    // S13: scalars
    if (b0 == 0 && threadIdx.x == 0) {
        float c = *p.cnt;
        float T = (float)*p.tot;
        float R = (float)*p.tr;
        bool has = c > 0.f;
        p.o_sc[0] = has ? (T / fmaxf(c, 1.f)) : 0.f;
        p.o_sc[1] = has ? (2.f * T / (R * (R - 1.f) + 1e-4f)) : 0.f;
        p.o_sc[2] = has ? R : 0.f;
    }
}

// ---------------------------------------------------------------------------
// Classic multi-dispatch fallback (used only if cooperative launch is rejected).
__global__ __launch_bounds__(256) void k_stage0(const float* adj, int* cols, int* rowcnt,
                                                const float* Fda, const float* W1da, float* X1,
                                                const float* Fq, const float* W1q, float* Xq) {
    __shared__ SMem sm;
    int bid = blockIdx.x;
    if (bid < NB_BIG) gemm_body<false, false>(sm.g, bid >> 2, bid & 3, Fda, W1da, X1, NDA, D, DIN);
    else if (bid < NB_BIG + 4) gemm_body<false, false>(sm.g, 0, bid - NB_BIG, Fq, W1q, Xq, NQ, D, DIN);
    else csr_body(sm.z, adj, cols, rowcnt, bid - (NB_BIG + 4));
}
__global__ __launch_bounds__(256) void k_sg(const int* cols, const int* rowcnt, const float* X,
                                            float* out1, float* out2,
                                            const float* Aq, const float* Bq, float* Cq) {
    __shared__ SMem sm;
    int bid = blockIdx.x;
    if (bid < 4) gemm_body<false, true>(sm.g, 0, bid, Aq, Bq, Cq, NQ, D, NQ);
    else spmm_body(sm.s, cols, rowcnt, X, out1, out2, bid - 4);
}
__global__ __launch_bounds__(256) void k_mergeA(const float* q1, const float* da1, const int* cand,
                                                float* hpart, const float* W2da, float* Y2) {
    __shared__ SMem sm;
    int bid = blockIdx.x;
    if (bid < 256) cross_body(sm.c, q1, da1, cand, hpart, bid >> 2, bid & 3);
    else { int t = bid - 256; gemm_body<true, false>(sm.g, t >> 2, t & 3, da1, W2da, Y2, NDA, D, D); }
}
__global__ __launch_bounds__(256) void k_cross(const float* q, const float* da, const int* cand,
                                               float* hpart) {
    __shared__ SMem sm;
    cross_body(sm.c, q, da, cand, hpart, blockIdx.x, blockIdx.y);
}
__global__ __launch_bounds__(256) void k_attq(const float* q, const float* hpart, float* attq,
                                              float* emb) {
    __shared__ SMem sm;
    attq_body(sm.a, q, hpart, attq, emb);
}
__global__ __launch_bounds__(256) void k_gemmZ(const float* A, const float* B, float* C) {
    __shared__ SMem sm;
    gemm_body<false, false>(sm.g, 0, blockIdx.x, A, B, C, NQ, D, D);
}
__global__ __launch_bounds__(256) void k_end(const float* A, const float* emb, const float* thr,
                                             float* endv, float* m, float* cnt) {
    __shared__ SMem sm;
    end_body(sm.e, A, emb, thr, endv, m, cnt, blockIdx.x);
}
__global__ __launch_bounds__(256) void k_gpart(const float* A, const float* m, float* Gp) {
    __shared__ SMem sm;
    gpart_body(sm.gp, A, m, Gp, blockIdx.x, blockIdx.y);
}
__global__ __launch_bounds__(256) void k_gred(const float* Gp, float* G) {
    int idx = blockIdx.x * 256 + threadIdx.x;
    float s = 0.f;
#pragma unroll
    for (int c = 0; c < NCHUNK; c++) s += Gp[(size_t)c * D * D + idx];
    G[idx] = s;
}
__global__ __launch_bounds__(256) void k_gemmH(const float* A, const float* B, float* C) {
    __shared__ SMem sm;
    gemm_body<false, false>(sm.g, blockIdx.x, blockIdx.y, A, B, C, NDA, D, D);
}
__global__ __launch_bounds__(256) void k_final(const int* cols, const int* rowcnt, const float* m,
                                               const float* A, const float* H,
                                               double* total, double* tr) {
    __shared__ SMem sm;
    final_body(sm.f, cols, rowcnt, m, A, H, total, tr, blockIdx.x);
}
__global__ void k_scalars(const float* cnt, const double* total, const double* tr, float* out) {
    float c = *cnt;
    float T = (float)*total;
    float R = (float)*tr;
    bool has = c > 0.f;
    out[0] = has ? (T / fmaxf(c, 1.f)) : 0.f;
    out[1] = has ? (2.f * T / (R * (R - 1.f) + 1e-4f)) : 0.f;
    out[2] = has ? R : 0.f;
}

// ---------------------------------------------------------------------------
extern "C" void kernel_launch(void* const* d_in, const int* in_sizes, int n_in,
                              void* d_out, int out_size, void* d_ws, size_t ws_size,
                              hipStream_t stream) {
    (void)in_sizes; (void)n_in; (void)out_size; (void)ws_size;
    const float* adj  = (const float*)d_in[0];
    const float* Fda  = (const float*)d_in[1];
    const float* Qadj = (const float*)d_in[2];
    const float* Fq   = (const float*)d_in[3];
    const int*   cand = (const int*)d_in[4];
    // d_in[5] candidate_adj: unused by the reference
    const float* thr  = (const float*)d_in[6];
    const float* W1da = (const float*)d_in[7];
    const float* W1q  = (const float*)d_in[8];
    const float* W2da = (const float*)d_in[9];
    const float* W2q  = (const float*)d_in[10];

    float* out = (float*)d_out;
    float* o_end    = out;                           // [10000]
    float* o_attda2 = out + NDA;                     // [10000,256]
    float* o_attq2  = out + NDA + (size_t)NDA * D;   // [64,256]
    float* o_sc     = o_attq2 + NQ * D;              // [3] scalars

    char* w = (char*)d_ws;
    size_t off = 0;
    auto alloc = [&](size_t b) { size_t r = off; off += (b + 255) & ~(size_t)255; return r; };
    float* bufA = (float*)(w + alloc((size_t)NDA * D * 4));   // X1 -> Y2
    float* bufB = (float*)(w + alloc((size_t)NDA * D * 4));   // da1 -> H
    float* bufC = (float*)(w + alloc((size_t)NDA * D * 4));   // da2
    int* colsb   = (int*)(w + alloc((size_t)NDA * CAP * 4));
    int* rowcntb = (int*)(w + alloc((size_t)NDA * 4));
    float* mbuf  = (float*)(w + alloc((size_t)NDA * 4));
    float* Gb    = (float*)(w + alloc((size_t)D * D * 4));
    float* Gp    = (float*)(w + alloc((size_t)NCHUNK * D * D * 4));
    char* zbase = w + alloc(256);
    float* cntb  = (float*)zbase;
    double* totb = (double*)(zbase + 8);
    double* trb  = (double*)(zbase + 16);
    float* xq   = (float*)(w + alloc((size_t)NQ * D * 4));    // Xq -> Zq
    float* q1b  = (float*)(w + alloc((size_t)NQ * D * 4));
    float* aq1  = (float*)(w + alloc((size_t)NQ * D * 4));
    float* q2b  = (float*)(w + alloc((size_t)NQ * D * 4));
    float* hpart = (float*)(w + alloc((size_t)4 * NQ * D * 4));
    float* embb = (float*)(w + alloc((size_t)(D + 1) * 4));

    // Cooperative grid size: co-residency required. Query once.
    static int grid_blocks = 0;
    if (grid_blocks == 0) {
        int bpc = 0;
        if (hipOccupancyMaxActiveBlocksPerMultiprocessor(&bpc, mega, 256, 0) != hipSuccess || bpc <= 0)
            bpc = 2;   // conservative: 17.4 KB LDS, <=128 VGPR -> 2 blocks/CU always fits
        hipDeviceProp_t prop;
        int ncu = 256;
        if (hipGetDeviceProperties(&prop, 0) == hipSuccess && prop.multiProcessorCount > 0)
            ncu = prop.multiProcessorCount;
        grid_blocks = bpc * ncu;
        if (grid_blocks > 4096) grid_blocks = 4096;
        if (grid_blocks < 64) grid_blocks = 64;
    }

    P p = { adj, Fda, Qadj, Fq, cand, thr, W1da, W1q, W2da, W2q,
            o_end, o_attda2, o_attq2, o_sc,
            bufA, bufB, bufC, colsb, rowcntb,
            mbuf, Gb, Gp, cntb, totb, trb,
            xq, q1b, aq1, q2b, hpart, embb };
    void* args[] = { &p };
    hipError_t ce = hipLaunchCooperativeKernel((const void*)mega, dim3(grid_blocks), dim3(256),
                                               args, 0u, stream);
    if (ce == hipSuccess) return;
    (void)hipGetLastError();   // clear sticky error; run classic fallback

    hipMemsetAsync(zbase, 0, 256, stream);
    k_stage0<<<NB_BIG + 4 + NDA, 256, 0, stream>>>(adj, colsb, rowcntb, Fda, W1da, bufA, Fq, W1q, xq);
    k_sg<<<NDA + 4, 256, 0, stream>>>(colsb, rowcntb, bufA, bufB, (float*)nullptr, Qadj, xq, q1b);
    k_mergeA<<<256 + NB_BIG, 256, 0, stream>>>(q1b, bufB, cand, hpart, W2da, bufA);
    k_attq<<<1, 256, 0, stream>>>(q1b, hpart, aq1, (float*)nullptr);
    k_gemmZ<<<4, 256, 0, stream>>>(aq1, W2q, xq);
    k_sg<<<NDA + 4, 256, 0, stream>>>(colsb, rowcntb, bufA, bufC, o_attda2, Qadj, xq, q2b);
    k_cross<<<dim3(NQ, 4), 256, 0, stream>>>(q2b, bufC, cand, hpart);
    k_attq<<<1, 256, 0, stream>>>(q2b, hpart, o_attq2, embb);
    k_end<<<NDA / 4, 256, 0, stream>>>(o_attda2, embb, thr, o_end, mbuf, cntb);
    k_gpart<<<dim3(16, NCHUNK), 256, 0, stream>>>(o_attda2, mbuf, Gp);
    k_gred<<<D * D / 256, 256, 0, stream>>>(Gp, Gb);
    k_gemmH<<<dim3((NDA + 63) / 64, D / 64), 256, 0, stream>>>(o_attda2, Gb, bufB);
    k_final<<<NDA, 256, 0, stream>>>(colsb, rowcntb, mbuf, o_attda2, bufB, totb, trb);
    k_scalars<<<1, 1, 0, stream>>>(cntb, totb, trb, o_sc);
}

// Round 4
// 1261.231 us; speedup vs baseline: 1.4191x; 1.4191x over previous
//
#include <hip/hip_runtime.h>

// Problem constants (fixed by setup_inputs)
constexpr int NDA = 10000;   // target graph nodes
constexpr int NQ  = 64;      // query graph nodes
constexpr int CND = 1024;    // candidate set size
constexpr int DIN = 128;     // input feature dim
constexpr int D   = 256;     // hidden dim
constexpr int CAP = 96;      // max nnz per adjacency row (Poisson(20); P(>96) ~ 0)
constexpr int NT128 = (NDA + 127) / 128;   // 79 row-tiles of 128
constexpr int NB128 = NT128 * 2;           // 158 blocks for 10000x256 gemm (2 col-tiles)
constexpr int NCHUNK = 32;
constexpr int GCHUNK = 320;                // 32*320 = 10240 >= NDA (guarded)

#define LRELU(x) ((x) >= 0.f ? (x) : 0.01f * (x))

__device__ __forceinline__ float wave_red64(float v) {
#pragma unroll
    for (int o = 32; o; o >>= 1) v += __shfl_down(v, o);
    return v;
}

// ---------------------------------------------------------------------------
// Shared-memory union (max ~18 KB), reused by every stage body.
struct GemmSmem    { float As[32][65]; float Bs[32][68]; };   // 64x64 tile gemm
struct Gemm128Smem { float As[16][132]; float Bs[16][132]; }; // 128x128 tile gemm
struct CrossSmem   { float qs[D]; float cmw[256]; int sci[256]; float red[4]; float sqn; };
struct SpmmSmem    { int sc[CAP]; };
struct CsrSmem     { int scnt; };
struct EndSmem     { float se[D]; float scnt; float red[4]; };
struct FinalSmem   { int sc[CAP]; float smask[CAP]; int sdiag; float r1[4], r2[4], r3[4]; };
struct Attq4Smem   { float hbuf[64][65]; float red[4][64]; float invs[64]; };
union SMem {
    GemmSmem g; Gemm128Smem h; CrossSmem c; SpmmSmem s; CsrSmem z;
    EndSmem e; FinalSmem f; Attq4Smem a;
};

// ---------------------------------------------------------------------------
// 64x64-tile GEMM (for the tiny 64-row q-path): 4x4/thread, K%32==0.
template <bool RELU_A, bool RELU_C>
__device__ __forceinline__ void gemm_body(GemmSmem& sm, int bx, int by,
                                          const float* __restrict__ A,
                                          const float* __restrict__ B,
                                          float* __restrict__ C,
                                          int M, int N, int K) {
    const int bm = bx * 64, bn = by * 64;
    const int tid = threadIdx.x;
    const int tx = tid & 15, ty = tid >> 4;
    const int lm = tid >> 2, lk = (tid & 3) * 8;
    const int kb = tid >> 3, nb = (tid & 7) * 8;
    const bool aValid = (bm + lm) < M;
    const float* aPtr = A + (size_t)(bm + lm) * K + lk;
    const float* bPtr = B + (size_t)kb * N + bn + nb;
    float4 ra0 = make_float4(0.f, 0.f, 0.f, 0.f), ra1 = ra0, rb0, rb1;
    if (aValid) { ra0 = *(const float4*)aPtr; ra1 = *(const float4*)(aPtr + 4); }
    rb0 = *(const float4*)bPtr;
    rb1 = *(const float4*)(bPtr + 4);
    float acc[4][4] = {};
    for (int k0 = 0; k0 < K; k0 += 32) {
        float4 wa0 = ra0, wa1 = ra1, wb0 = rb0, wb1 = rb1;
        if (RELU_A) {
            wa0.x = LRELU(wa0.x); wa0.y = LRELU(wa0.y); wa0.z = LRELU(wa0.z); wa0.w = LRELU(wa0.w);
            wa1.x = LRELU(wa1.x); wa1.y = LRELU(wa1.y); wa1.z = LRELU(wa1.z); wa1.w = LRELU(wa1.w);
        }
        sm.As[lk + 0][lm] = wa0.x; sm.As[lk + 1][lm] = wa0.y;
        sm.As[lk + 2][lm] = wa0.z; sm.As[lk + 3][lm] = wa0.w;
        sm.As[lk + 4][lm] = wa1.x; sm.As[lk + 5][lm] = wa1.y;
        sm.As[lk + 6][lm] = wa1.z; sm.As[lk + 7][lm] = wa1.w;
        *(float4*)&sm.Bs[kb][nb]     = wb0;
        *(float4*)&sm.Bs[kb][nb + 4] = wb1;
        __syncthreads();
        if (k0 + 32 < K) {
            if (aValid) {
                ra0 = *(const float4*)(aPtr + k0 + 32);
                ra1 = *(const float4*)(aPtr + k0 + 36);
            }
            rb0 = *(const float4*)(bPtr + (size_t)(k0 + 32) * N);
            rb1 = *(const float4*)(bPtr + (size_t)(k0 + 32) * N + 4);
        }
#pragma unroll
        for (int kk = 0; kk < 32; kk++) {
            float av[4], bv[4];
#pragma unroll
            for (int i = 0; i < 4; i++) av[i] = sm.As[kk][ty * 4 + i];
#pragma unroll
            for (int j = 0; j < 4; j++) bv[j] = sm.Bs[kk][tx * 4 + j];
#pragma unroll
            for (int i = 0; i < 4; i++)
#pragma unroll
                for (int j = 0; j < 4; j++) acc[i][j] += av[i] * bv[j];
        }
        __syncthreads();
    }
#pragma unroll
    for (int i = 0; i < 4; i++) {
        int r = bm + ty * 4 + i;
        if (r < M) {
            float4 v = make_float4(acc[i][0], acc[i][1], acc[i][2], acc[i][3]);
            if (RELU_C) { v.x = LRELU(v.x); v.y = LRELU(v.y); v.z = LRELU(v.z); v.w = LRELU(v.w); }
            *(float4*)(C + (size_t)r * N + bn + tx * 4) = v;
        }
    }
}

// ---------------------------------------------------------------------------
// 128x128-tile GEMM, 8x8 per thread, float4 LDS reads (LDS-issue relief).
// K % 16 == 0. Guarded rows at M edge. RELU_A optional on A-load.
template <bool RELU_A>
__device__ __forceinline__ void gemm128_body(Gemm128Smem& sm, int bx, int by,
                                             const float* __restrict__ A,
                                             const float* __restrict__ B,
                                             float* __restrict__ C,
                                             int M, int N, int K) {
    const int bm = bx * 128, bn = by * 128;
    const int tid = threadIdx.x;
    const int tx = tid & 15, ty = tid >> 4;
    const int am = tid >> 1, ak = (tid & 1) * 8;    // A-slab: 128 rows x 16 k
    const int bk = tid >> 4, bn8 = (tid & 15) * 8;  // B-slab: 16 k x 128 cols
    const bool aValid = (bm + am) < M;
    const float* aPtr = A + (size_t)(bm + am) * K + ak;
    const float* bPtr = B + (size_t)bk * N + bn + bn8;
    float4 ra0 = make_float4(0.f, 0.f, 0.f, 0.f), ra1 = ra0, rb0, rb1;
    if (aValid) { ra0 = *(const float4*)aPtr; ra1 = *(const float4*)(aPtr + 4); }
    rb0 = *(const float4*)bPtr;
    rb1 = *(const float4*)(bPtr + 4);
    float acc[8][8] = {};
    for (int k0 = 0; k0 < K; k0 += 16) {
        float a8[8] = { ra0.x, ra0.y, ra0.z, ra0.w, ra1.x, ra1.y, ra1.z, ra1.w };
        if (RELU_A) {
#pragma unroll
            for (int j = 0; j < 8; j++) a8[j] = LRELU(a8[j]);
        }
#pragma unroll
        for (int j = 0; j < 8; j++) sm.As[ak + j][am] = a8[j];
        *(float4*)&sm.Bs[bk][bn8]     = rb0;
        *(float4*)&sm.Bs[bk][bn8 + 4] = rb1;
        __syncthreads();
        if (k0 + 16 < K) {
            if (aValid) {
                ra0 = *(const float4*)(aPtr + k0 + 16);
                ra1 = *(const float4*)(aPtr + k0 + 20);
            }
            rb0 = *(const float4*)(bPtr + (size_t)(k0 + 16) * N);
            rb1 = *(const float4*)(bPtr + (size_t)(k0 + 16) * N + 4);
        }
#pragma unroll
        for (int kk = 0; kk < 16; kk++) {
            float4 a0 = *(const float4*)&sm.As[kk][ty * 8];
            float4 a1 = *(const float4*)&sm.As[kk][ty * 8 + 4];
            float4 b0 = *(const float4*)&sm.Bs[kk][tx * 8];
            float4 b1 = *(const float4*)&sm.Bs[kk][tx * 8 + 4];
            float av[8] = { a0.x, a0.y, a0.z, a0.w, a1.x, a1.y, a1.z, a1.w };
            float bv[8] = { b0.x, b0.y, b0.z, b0.w, b1.x, b1.y, b1.z, b1.w };
#pragma unroll
            for (int i = 0; i < 8; i++)
#pragma unroll
                for (int j = 0; j < 8; j++) acc[i][j] += av[i] * bv[j];
        }
        __syncthreads();
    }
#pragma unroll
    for (int i = 0; i < 8; i++) {
        int r = bm + ty * 8 + i;
        if (r < M) {
            float4 v0 = make_float4(acc[i][0], acc[i][1], acc[i][2], acc[i][3]);
            float4 v1 = make_float4(acc[i][4], acc[i][5], acc[i][6], acc[i][7]);
            *(float4*)(C + (size_t)r * N + bn + tx * 8)     = v0;
            *(float4*)(C + (size_t)r * N + bn + tx * 8 + 4) = v1;
        }
    }
}

// ---------------------------------------------------------------------------
__device__ __forceinline__ void csr_body(CsrSmem& sm, const float* __restrict__ adj,
                                         int* __restrict__ cols,
                                         int* __restrict__ rowcnt, int row) {
    if (threadIdx.x == 0) sm.scnt = 0;
    __syncthreads();
    const float4* rp = (const float4*)(adj + (size_t)row * NDA);
    for (int i = threadIdx.x; i < NDA / 4; i += 256) {
        float4 v = rp[i];
        if (v.x != 0.f) { int s = atomicAdd(&sm.scnt, 1); if (s < CAP) cols[row * CAP + s] = 4 * i; }
        if (v.y != 0.f) { int s = atomicAdd(&sm.scnt, 1); if (s < CAP) cols[row * CAP + s] = 4 * i + 1; }
        if (v.z != 0.f) { int s = atomicAdd(&sm.scnt, 1); if (s < CAP) cols[row * CAP + s] = 4 * i + 2; }
        if (v.w != 0.f) { int s = atomicAdd(&sm.scnt, 1); if (s < CAP) cols[row * CAP + s] = 4 * i + 3; }
    }
    __syncthreads();
    if (threadIdx.x == 0) rowcnt[row] = min(sm.scnt, CAP);
}

// ---------------------------------------------------------------------------
__device__ __forceinline__ void spmm_body(SpmmSmem& sm, const int* __restrict__ cols,
                                          const int* __restrict__ rowcnt,
                                          const float* __restrict__ X,
                                          float* __restrict__ out1,
                                          float* __restrict__ out2, int row) {
    int d = threadIdx.x;
    int cnt = rowcnt[row];
    if (d < cnt) sm.sc[d] = cols[row * CAP + d];
    __syncthreads();
    float a0 = 0.f, a1 = 0.f, a2 = 0.f, a3 = 0.f;
    int k = 0;
    for (; k + 4 <= cnt; k += 4) {
        a0 += X[(size_t)sm.sc[k + 0] * D + d];
        a1 += X[(size_t)sm.sc[k + 1] * D + d];
        a2 += X[(size_t)sm.sc[k + 2] * D + d];
        a3 += X[(size_t)sm.sc[k + 3] * D + d];
    }
    for (; k < cnt; k++) a0 += X[(size_t)sm.sc[k] * D + d];
    float v = LRELU(a0 + a1 + a2 + a3);
    out1[(size_t)row * D + d] = v;
    if (out2) out2[(size_t)row * D + d] = LRELU(v);
}

// ---------------------------------------------------------------------------
__device__ __forceinline__ void cross_body(CrossSmem& sm, const float* __restrict__ q,
                                           const float* __restrict__ da,
                                           const int* __restrict__ cand,
                                           float* __restrict__ hpart,
                                           int r, int qr) {
    int d = threadIdx.x;
    float qv = q[r * D + d];
    sm.qs[d] = qv;
    sm.sci[d] = cand[qr * 256 + d];
    float p = wave_red64(qv * qv);
    int w = d >> 6, lane = d & 63;
    if (lane == 0) sm.red[w] = p;
    __syncthreads();
    if (d == 0) sm.sqn = fmaxf(sqrtf(sm.red[0] + sm.red[1] + sm.red[2] + sm.red[3]), 1e-12f);
    __syncthreads();
    float qn = sm.sqn;
    {
        const float4* ap = (const float4*)(da + (size_t)sm.sci[d] * D);
        float dot = 0.f, sq = 0.f;
#pragma unroll 8
        for (int k = 0; k < D / 4; k++) {
            float4 v = ap[k];
            dot += sm.qs[4 * k] * v.x + sm.qs[4 * k + 1] * v.y + sm.qs[4 * k + 2] * v.z + sm.qs[4 * k + 3] * v.w;
            sq  += v.x * v.x + v.y * v.y + v.z * v.z + v.w * v.w;
        }
        sm.cmw[d] = dot / (qn * fmaxf(sqrtf(sq), 1e-12f));
    }
    __syncthreads();
    float a0 = 0.f, a1 = 0.f, a2 = 0.f, a3 = 0.f, a4 = 0.f, a5 = 0.f, a6 = 0.f, a7 = 0.f;
    for (int c = 0; c < 256; c += 8) {
        a0 += sm.cmw[c + 0] * da[(size_t)sm.sci[c + 0] * D + d];
        a1 += sm.cmw[c + 1] * da[(size_t)sm.sci[c + 1] * D + d];
        a2 += sm.cmw[c + 2] * da[(size_t)sm.sci[c + 2] * D + d];
        a3 += sm.cmw[c + 3] * da[(size_t)sm.sci[c + 3] * D + d];
        a4 += sm.cmw[c + 4] * da[(size_t)sm.sci[c + 4] * D + d];
        a5 += sm.cmw[c + 5] * da[(size_t)sm.sci[c + 5] * D + d];
        a6 += sm.cmw[c + 6] * da[(size_t)sm.sci[c + 6] * D + d];
        a7 += sm.cmw[c + 7] * da[(size_t)sm.sci[c + 7] * D + d];
    }
    hpart[((size_t)qr * NQ + r) * D + d] = ((a0 + a1) + (a2 + a3)) + ((a4 + a5) + (a6 + a7));
}

// ---------------------------------------------------------------------------
// Stage 0: [X1 gemm128 | Xq gemm64 | CSR build]
__global__ __launch_bounds__(256) void stage0_kernel(const float* __restrict__ adj,
                                                     int* __restrict__ cols,
                                                     int* __restrict__ rowcnt,
                                                     const float* __restrict__ Fda,
                                                     const float* __restrict__ W1da,
                                                     float* __restrict__ X1,
                                                     const float* __restrict__ Fq,
                                                     const float* __restrict__ W1q,
                                                     float* __restrict__ Xq) {
    __shared__ SMem sm;
    int bid = blockIdx.x;
    if (bid < NB128) {
        gemm128_body<false>(sm.h, bid >> 1, bid & 1, Fda, W1da, X1, NDA, D, DIN);
    } else if (bid < NB128 + 4) {
        gemm_body<false, false>(sm.g, 0, bid - NB128, Fq, W1q, Xq, NQ, D, DIN);
    } else {
        csr_body(sm.z, adj, cols, rowcnt, bid - (NB128 + 4));
    }
}

// [q-gemm (Qadj @ xq, lrelu) | spmm over all target rows]
__global__ __launch_bounds__(256) void stage_sg_kernel(const int* __restrict__ cols,
                                                       const int* __restrict__ rowcnt,
                                                       const float* __restrict__ X,
                                                       float* __restrict__ out1,
                                                       float* __restrict__ out2,
                                                       const float* __restrict__ Aq,
                                                       const float* __restrict__ Bq,
                                                       float* __restrict__ Cq) {
    __shared__ SMem sm;
    int bid = blockIdx.x;
    if (bid < 4) {
        gemm_body<false, true>(sm.g, 0, bid, Aq, Bq, Cq, NQ, D, NQ);
    } else {
        spmm_body(sm.s, cols, rowcnt, X, out1, out2, bid - 4);
    }
}

// [cross1 | Y2 = lrelu(da1) @ W2da via gemm128]
__global__ __launch_bounds__(256) void mergeA_kernel(const float* __restrict__ q1,
                                                     const float* __restrict__ da1,
                                                     const int* __restrict__ cand,
                                                     float* __restrict__ hpart,
                                                     const float* __restrict__ W2da,
                                                     float* __restrict__ Y2) {
    __shared__ SMem sm;
    int bid = blockIdx.x;
    if (bid < 256) {
        cross_body(sm.c, q1, da1, cand, hpart, bid >> 2, bid & 3);
    } else {
        int t = bid - 256;
        gemm128_body<true>(sm.h, t >> 1, t & 1, da1, W2da, Y2, NDA, D, D);
    }
}

// Standalone cross (layer 2)
__global__ __launch_bounds__(256) void cross_kernel(const float* __restrict__ q,
                                                    const float* __restrict__ da,
                                                    const int* __restrict__ cand,
                                                    float* __restrict__ hpart) {
    __shared__ SMem sm;
    cross_body(sm.c, q, da, cand, hpart, blockIdx.x, blockIdx.y);
}

// ---------------------------------------------------------------------------
// qfused: attq1 computed straight into LDS (A^T layout), then Zq = aq1 @ W2q.
__global__ __launch_bounds__(256) void qfused_kernel(const float* __restrict__ q,
                                                     const float* __restrict__ hpart,
                                                     const float* __restrict__ W2q,
                                                     float* __restrict__ Zq) {
    __shared__ float aqT[D][65];   // A^T: [k][m], m = query row
    __shared__ float Bs[32][68];
    int d = threadIdx.x;
    float hv[NQ];
    float ss = 0.f;
#pragma unroll
    for (int r = 0; r < NQ; r++) {
        float h = hpart[(size_t)r * D + d]
                + hpart[(size_t)(NQ + r) * D + d]
                + hpart[(size_t)(2 * NQ + r) * D + d]
                + hpart[(size_t)(3 * NQ + r) * D + d];
        hv[r] = h;
        ss += h * h;
    }
    float inv = 1.f / fmaxf(sqrtf(ss), 1e-12f);
#pragma unroll
    for (int r = 0; r < NQ; r++) {
        float v = q[r * D + d] + hv[r] * inv;
        aqT[d][r] = LRELU(v);
    }
    __syncthreads();
    const int bn = blockIdx.x * 64;
    const int tx = d & 15, ty = d >> 4;
    const int kb = d >> 3, nb = (d & 7) * 8;
    float acc[4][4] = {};
    for (int k0 = 0; k0 < D; k0 += 32) {
        float4 b0 = *(const float4*)(W2q + (size_t)(k0 + kb) * D + bn + nb);
        float4 b1 = *(const float4*)(W2q + (size_t)(k0 + kb) * D + bn + nb + 4);
        *(float4*)&Bs[kb][nb]     = b0;
        *(float4*)&Bs[kb][nb + 4] = b1;
        __syncthreads();
#pragma unroll
        for (int kk = 0; kk < 32; kk++) {
            float av[4], bv[4];
#pragma unroll
            for (int i = 0; i < 4; i++) av[i] = aqT[k0 + kk][ty * 4 + i];
#pragma unroll
            for (int j = 0; j < 4; j++) bv[j] = Bs[kk][tx * 4 + j];
#pragma unroll
            for (int i = 0; i < 4; i++)
#pragma unroll
                for (int j = 0; j < 4; j++) acc[i][j] += av[i] * bv[j];
        }
        __syncthreads();
    }
#pragma unroll
    for (int i = 0; i < 4; i++) {
        float4 v = make_float4(acc[i][0], acc[i][1], acc[i][2], acc[i][3]);
        *(float4*)(Zq + (size_t)(ty * 4 + i) * D + bn + tx * 4) = v;
    }
}

// ---------------------------------------------------------------------------
// attq (4 blocks, 64 columns each): att_q2 = lrelu(q + h/colnorm(h)), emb = col
// means. Block 0 thread 0 also zero-inits the scalar accumulators + done flag.
__global__ __launch_bounds__(256) void attq4_kernel(const float* __restrict__ q,
                                                    const float* __restrict__ hpart,
                                                    float* __restrict__ attq,
                                                    float* __restrict__ emb,
                                                    float* __restrict__ cnt,
                                                    double* __restrict__ tot,
                                                    double* __restrict__ tr,
                                                    int* __restrict__ done) {
    __shared__ SMem smu;
    Attq4Smem& sm = smu.a;
    int b = blockIdx.x, t = threadIdx.x;
    int lc = t & 63, rq = t >> 6;
    int c = b * 64 + lc;
    if (b == 0 && t == 0) { *cnt = 0.f; *tot = 0.0; *tr = 0.0; *done = 0; }
    float ss = 0.f;
#pragma unroll
    for (int rr = 0; rr < 16; rr++) {
        int r = rq * 16 + rr;
        float h = hpart[(size_t)r * D + c]
                + hpart[(size_t)(NQ + r) * D + c]
                + hpart[(size_t)(2 * NQ + r) * D + c]
                + hpart[(size_t)(3 * NQ + r) * D + c];
        sm.hbuf[r][lc] = h;
        ss += h * h;
    }
    sm.red[rq][lc] = ss;
    __syncthreads();
    if (rq == 0) {
        float s = sm.red[0][lc] + sm.red[1][lc] + sm.red[2][lc] + sm.red[3][lc];
        sm.invs[lc] = 1.f / fmaxf(sqrtf(s), 1e-12f);
    }
    __syncthreads();
    float inv = sm.invs[lc];
    float es = 0.f;
#pragma unroll
    for (int rr = 0; rr < 16; rr++) {
        int r = rq * 16 + rr;
        float v = q[r * D + c] + sm.hbuf[r][lc] * inv;
        v = LRELU(v);
        attq[r * D + c] = v;
        es += v;
    }
    __syncthreads();   // red[] reuse
    sm.red[rq][lc] = es;
    __syncthreads();
    if (rq == 0) {
        float e = (sm.red[0][lc] + sm.red[1][lc] + sm.red[2][lc] + sm.red[3][lc]) * (1.f / (float)NQ);
        emb[c] = e;
    }
}

// ---------------------------------------------------------------------------
// end[i] = (a_i . emb) / max(|a_i|*|emb|, 1e-8); embn recomputed in-block.
__global__ __launch_bounds__(256) void end_kernel(const float* __restrict__ A,
                                                  const float* __restrict__ emb,
                                                  const float* __restrict__ thr_p,
                                                  float* __restrict__ endv,
                                                  float* __restrict__ m,
                                                  float* __restrict__ cnt) {
    __shared__ SMem smu;
    EndSmem& sm = smu.e;
    int d = threadIdx.x;
    float ev = emb[d];
    sm.se[d] = ev;
    if (d == 0) sm.scnt = 0.f;
    int w = d >> 6, lane = d & 63;
    float pe = wave_red64(ev * ev);
    if (lane == 0) sm.red[w] = pe;
    __syncthreads();
    float embn = sqrtf(sm.red[0] + sm.red[1] + sm.red[2] + sm.red[3]);
    float thr = *thr_p;
    int row = blockIdx.x * 4 + w;
    const float* ar = A + (size_t)row * D;
    float num = 0.f, sq = 0.f;
#pragma unroll
    for (int s = 0; s < 4; s++) {
        float v = ar[lane + 64 * s];
        num += v * sm.se[lane + 64 * s];
        sq += v * v;
    }
#pragma unroll
    for (int o = 32; o; o >>= 1) { num += __shfl_down(num, o); sq += __shfl_down(sq, o); }
    if (lane == 0) {
        float den = fmaxf(sqrtf(sq) * embn, 1e-8f);
        float e = num / den;
        endv[row] = e;
        float mv = e > thr ? 1.f : 0.f;
        m[row] = mv;
        if (mv != 0.f) atomicAdd(&sm.scnt, 1.f);
    }
    __syncthreads();
    if (d == 0 && sm.scnt != 0.f) atomicAdd(cnt, sm.scnt);
}

// ---------------------------------------------------------------------------
// G partials, 128x128 tiles, 8x8/thread: Gp[c] = sum_{i in chunk c, m_i} a_i a_i^T.
// grid (4 tiles, NCHUNK chunks).
__global__ __launch_bounds__(256) void Gpart_kernel(const float* __restrict__ A,
                                                    const float* __restrict__ m,
                                                    float* __restrict__ Gp) {
    __shared__ SMem smu;
    Gemm128Smem& sm = smu.h;
    int ti = blockIdx.x >> 1, tj = blockIdx.x & 1;
    int base = blockIdx.y * GCHUNK;
    int tid = threadIdx.x;
    int tx = tid & 15, ty = tid >> 4;
    int sr = tid >> 4, sc8 = (tid & 15) * 8;
    float acc[8][8] = {};
    for (int g0 = 0; g0 < GCHUNK; g0 += 16) {
        int r = base + g0 + sr;
        float4 va0 = make_float4(0.f, 0.f, 0.f, 0.f), va1 = va0, vb0 = va0, vb1 = va0;
        float mv = 0.f;
        if (r < NDA) {
            mv = m[r];
            const float* ar = A + (size_t)r * D;
            va0 = *(const float4*)(ar + ti * 128 + sc8);
            va1 = *(const float4*)(ar + ti * 128 + sc8 + 4);
            vb0 = *(const float4*)(ar + tj * 128 + sc8);
            vb1 = *(const float4*)(ar + tj * 128 + sc8 + 4);
        }
        va0.x *= mv; va0.y *= mv; va0.z *= mv; va0.w *= mv;
        va1.x *= mv; va1.y *= mv; va1.z *= mv; va1.w *= mv;
        *(float4*)&sm.As[sr][sc8]     = va0;
        *(float4*)&sm.As[sr][sc8 + 4] = va1;
        *(float4*)&sm.Bs[sr][sc8]     = vb0;
        *(float4*)&sm.Bs[sr][sc8 + 4] = vb1;
        __syncthreads();
#pragma unroll
        for (int kk = 0; kk < 16; kk++) {
            float4 a0 = *(const float4*)&sm.As[kk][ty * 8];
            float4 a1 = *(const float4*)&sm.As[kk][ty * 8 + 4];
            float4 b0 = *(const float4*)&sm.Bs[kk][tx * 8];
            float4 b1 = *(const float4*)&sm.Bs[kk][tx * 8 + 4];
            float av[8] = { a0.x, a0.y, a0.z, a0.w, a1.x, a1.y, a1.z, a1.w };
            float bv[8] = { b0.x, b0.y, b0.z, b0.w, b1.x, b1.y, b1.z, b1.w };
#pragma unroll
            for (int i = 0; i < 8; i++)
#pragma unroll
                for (int j = 0; j < 8; j++) acc[i][j] += av[i] * bv[j];
        }
        __syncthreads();
    }
    float* gp = Gp + (size_t)blockIdx.y * D * D;
#pragma unroll
    for (int i = 0; i < 8; i++) {
        int gi = ti * 128 + ty * 8 + i;
        float4 v0 = make_float4(acc[i][0], acc[i][1], acc[i][2], acc[i][3]);
        float4 v1 = make_float4(acc[i][4], acc[i][5], acc[i][6], acc[i][7]);
        *(float4*)(gp + (size_t)gi * D + tj * 128 + tx * 8)     = v0;
        *(float4*)(gp + (size_t)gi * D + tj * 128 + tx * 8 + 4) = v1;
    }
}

// Reduce the NCHUNK partials into G. grid D*D/256 blocks.
__global__ __launch_bounds__(256) void Gred_kernel(const float* __restrict__ Gp,
                                                   float* __restrict__ G) {
    int idx = blockIdx.x * 256 + threadIdx.x;
    float s = 0.f;
#pragma unroll
    for (int c = 0; c < NCHUNK; c++) s += Gp[(size_t)c * D * D + idx];
    G[idx] = s;
}

// H = att_da2 @ G  (gemm128)
__global__ __launch_bounds__(256) void gemmH_kernel(const float* __restrict__ A,
                                                    const float* __restrict__ B,
                                                    float* __restrict__ C) {
    __shared__ SMem sm;
    gemm128_body<false>(sm.h, blockIdx.x >> 1, blockIdx.x & 1, A, B, C, NDA, D, D);
}

// ---------------------------------------------------------------------------
// Final reduction; last block (done-counter) computes the 3 output scalars.
__global__ __launch_bounds__(256) void final_kernel(const int* __restrict__ cols,
                                                    const int* __restrict__ rowcnt,
                                                    const float* __restrict__ m,
                                                    const float* __restrict__ A,
                                                    const float* __restrict__ H,
                                                    double* __restrict__ total,
                                                    double* __restrict__ tr,
                                                    float* __restrict__ cnt,
                                                    int* __restrict__ done,
                                                    float* __restrict__ o_sc) {
    __shared__ SMem smu;
    FinalSmem& sm = smu.f;
    int i = blockIdx.x;
    int d = threadIdx.x;
    if (m[i] != 0.f) {
        int cnt_r = rowcnt[i];
        if (d == 0) sm.sdiag = 0;
        if (d < cnt_r) {
            int j = cols[i * CAP + d];
            sm.sc[d] = j;
            sm.smask[d] = m[j];
            if (j == i) sm.sdiag = 1;
        }
        __syncthreads();
        float av = A[(size_t)i * D + d];
        float hv = H[(size_t)i * D + d];
        float sd = 0.f;
        for (int k = 0; k < cnt_r; k++)
            if (sm.smask[k] != 0.f) sd += A[(size_t)sm.sc[k] * D + d];
        float p1 = av * sd, p2 = av * hv, p3 = av * av;
#pragma unroll
        for (int o = 32; o; o >>= 1) {
            p1 += __shfl_down(p1, o);
            p2 += __shfl_down(p2, o);
            p3 += __shfl_down(p3, o);
        }
        int w = d >> 6, lane = d & 63;
        if (lane == 0) { sm.r1[w] = p1; sm.r2[w] = p2; sm.r3[w] = p3; }
        __syncthreads();
        if (d == 0) {
            float num  = sm.r1[0] + sm.r1[1] + sm.r1[2] + sm.r1[3];
            float den2 = sm.r2[0] + sm.r2[1] + sm.r2[2] + sm.r2[3];
            float self = sm.r3[0] + sm.r3[1] + sm.r3[2] + sm.r3[3];
            float denom = fmaxf(sqrtf(den2), 1e-12f);
            double inv = 1.0 / (double)denom;
            if (num != 0.f) atomicAdd(total, (double)num * inv);
            if (sm.sdiag) atomicAdd(tr, (double)self * inv);
        }
    }
    // completion signal; last block computes the scalars (coherent atomic reads)
    if (d == 0) {
        __threadfence();
        int prev = atomicAdd(done, 1);
        if (prev == NDA - 1) {
            float c = atomicAdd(cnt, 0.f);
            float T = (float)atomicAdd(total, 0.0);
            float R = (float)atomicAdd(tr, 0.0);
            bool has = c > 0.f;
            o_sc[0] = has ? (T / fmaxf(c, 1.f)) : 0.f;                  // pre_avg_degree
            o_sc[1] = has ? (2.f * T / (R * (R - 1.f) + 1e-4f)) : 0.f;  // pre_density
            o_sc[2] = has ? R : 0.f;                                     // pre_avg_nodes
        }
    }
}

// ---------------------------------------------------------------------------
extern "C" void kernel_launch(void* const* d_in, const int* in_sizes, int n_in,
                              void* d_out, int out_size, void* d_ws, size_t ws_size,
                              hipStream_t stream) {
    (void)in_sizes; (void)n_in; (void)out_size; (void)ws_size;
    const float* adj  = (const float*)d_in[0];
    const float* Fda  = (const float*)d_in[1];
    const float* Qadj = (const float*)d_in[2];
    const float* Fq   = (const float*)d_in[3];
    const int*   cand = (const int*)d_in[4];
    // d_in[5] candidate_adj: unused by the reference
    const float* thr  = (const float*)d_in[6];
    const float* W1da = (const float*)d_in[7];
    const float* W1q  = (const float*)d_in[8];
    const float* W2da = (const float*)d_in[9];
    const float* W2q  = (const float*)d_in[10];

    float* out = (float*)d_out;
    float* o_end    = out;                           // [10000]
    float* o_attda2 = out + NDA;                     // [10000,256]
    float* o_attq2  = out + NDA + (size_t)NDA * D;   // [64,256]
    float* o_sc     = o_attq2 + NQ * D;              // [3] scalars

    char* w = (char*)d_ws;
    size_t off = 0;
    auto alloc = [&](size_t b) { size_t r = off; off += (b + 255) & ~(size_t)255; return r; };
    float* bufA = (float*)(w + alloc((size_t)NDA * D * 4));   // X1 -> Y2
    float* bufB = (float*)(w + alloc((size_t)NDA * D * 4));   // da1 -> H
    float* bufC = (float*)(w + alloc((size_t)NDA * D * 4));   // da2
    int* colsb   = (int*)(w + alloc((size_t)NDA * CAP * 4));
    int* rowcntb = (int*)(w + alloc((size_t)NDA * 4));
    float* mbuf  = (float*)(w + alloc((size_t)NDA * 4));
    float* Gb    = (float*)(w + alloc((size_t)D * D * 4));            // reduced G
    float* Gp    = (float*)(w + alloc((size_t)NCHUNK * D * D * 4));   // G partials
    char* zbase = w + alloc(256);                                     // scalar accumulators
    float* cntb  = (float*)zbase;
    double* totb = (double*)(zbase + 8);
    double* trb  = (double*)(zbase + 16);
    int*    doneb = (int*)(zbase + 24);
    float* xq   = (float*)(w + alloc((size_t)NQ * D * 4));    // Xq -> Zq
    float* q1b  = (float*)(w + alloc((size_t)NQ * D * 4));
    float* q2b  = (float*)(w + alloc((size_t)NQ * D * 4));
    float* hpart = (float*)(w + alloc((size_t)4 * NQ * D * 4));
    float* embb = (float*)(w + alloc((size_t)(D + 1) * 4));

    // Layer 1
    stage0_kernel<<<NB128 + 4 + NDA, 256, 0, stream>>>(adj, colsb, rowcntb,
                                                       Fda, W1da, bufA, Fq, W1q, xq);
    stage_sg_kernel<<<NDA + 4, 256, 0, stream>>>(colsb, rowcntb, bufA, bufB, (float*)nullptr,
                                                 Qadj, xq, q1b);                   // q1 | da1
    mergeA_kernel<<<256 + NB128, 256, 0, stream>>>(q1b, bufB, cand, hpart, W2da, bufA); // cross1 | Y2
    qfused_kernel<<<4, 256, 0, stream>>>(q1b, hpart, W2q, xq);                     // att_q1 -> Zq
    // Layer 2
    stage_sg_kernel<<<NDA + 4, 256, 0, stream>>>(colsb, rowcntb, bufA, bufC, o_attda2,
                                                 Qadj, xq, q2b);                   // q2 | da2
    cross_kernel<<<dim3(NQ, 4), 256, 0, stream>>>(q2b, bufC, cand, hpart);
    attq4_kernel<<<4, 256, 0, stream>>>(q2b, hpart, o_attq2, embb, cntb, totb, trb, doneb);
    // Scoring
    end_kernel<<<NDA / 4, 256, 0, stream>>>(o_attda2, embb, thr, o_end, mbuf, cntb);
    Gpart_kernel<<<dim3(4, NCHUNK), 256, 0, stream>>>(o_attda2, mbuf, Gp);
    Gred_kernel<<<D * D / 256, 256, 0, stream>>>(Gp, Gb);
    gemmH_kernel<<<NB128, 256, 0, stream>>>(o_attda2, Gb, bufB);                   // H = A @ G
    final_kernel<<<NDA, 256, 0, stream>>>(colsb, rowcntb, mbuf, o_attda2, bufB,
                                          totb, trb, cntb, doneb, o_sc);
}

// Round 5
// 1095.820 us; speedup vs baseline: 1.6333x; 1.1509x over previous
//
#include <hip/hip_runtime.h>

// Problem constants (fixed by setup_inputs)
constexpr int NDA = 10000;   // target graph nodes
constexpr int NQ  = 64;      // query graph nodes
constexpr int CND = 1024;    // candidate set size
constexpr int DIN = 128;     // input feature dim
constexpr int D   = 256;     // hidden dim
constexpr int CAP = 96;      // max nnz per adjacency row (Poisson(20); P(>96) ~ 0)
constexpr int NT128 = (NDA + 127) / 128;   // 79 row-tiles of 128
constexpr int NB128 = NT128 * 2;           // 158 blocks for 10000x256 gemm (2 col-tiles)
constexpr int NCHUNK = 32;
constexpr int GCHUNK = 320;                // 32*320 = 10240 >= NDA (guarded)

#define LRELU(x) ((x) >= 0.f ? (x) : 0.01f * (x))

__device__ __forceinline__ float wave_red64(float v) {
#pragma unroll
    for (int o = 32; o; o >>= 1) v += __shfl_down(v, o);
    return v;
}

// ---------------------------------------------------------------------------
// Per-stage shared-memory structs (each kernel declares only what it needs).
struct GemmSmem    { float As[32][65]; float Bs[32][68]; };   // 64x64 tile gemm
struct Gemm128Smem { float As[16][132]; float Bs[16][132]; }; // 128x128 tile gemm
struct CrossSmem   { float qs[D]; float cmw[256]; int sci[256]; float red[4]; float sqn; float part[4][256]; };
struct SpmmSmem    { int sc[CAP]; float part[4][256]; };
struct CsrSmem     { int scnt; };
struct EndSmem     { float se[D]; float scnt; float red[4]; };
struct FinalSmem   { int sc[CAP]; float part[4][256]; int n; int sdiag; float r1[4], r2[4], r3[4]; };
struct Attq4Smem   { float hbuf[64][65]; float red[4][64]; float invs[64]; };

// ---------------------------------------------------------------------------
// 64x64-tile GEMM (for the tiny 64-row q-path): 4x4/thread, K%32==0.
template <bool RELU_A, bool RELU_C>
__device__ __forceinline__ void gemm_body(GemmSmem& sm, int bx, int by,
                                          const float* __restrict__ A,
                                          const float* __restrict__ B,
                                          float* __restrict__ C,
                                          int M, int N, int K) {
    const int bm = bx * 64, bn = by * 64;
    const int tid = threadIdx.x;
    const int tx = tid & 15, ty = tid >> 4;
    const int lm = tid >> 2, lk = (tid & 3) * 8;
    const int kb = tid >> 3, nb = (tid & 7) * 8;
    const bool aValid = (bm + lm) < M;
    const float* aPtr = A + (size_t)(bm + lm) * K + lk;
    const float* bPtr = B + (size_t)kb * N + bn + nb;
    float4 ra0 = make_float4(0.f, 0.f, 0.f, 0.f), ra1 = ra0, rb0, rb1;
    if (aValid) { ra0 = *(const float4*)aPtr; ra1 = *(const float4*)(aPtr + 4); }
    rb0 = *(const float4*)bPtr;
    rb1 = *(const float4*)(bPtr + 4);
    float acc[4][4] = {};
    for (int k0 = 0; k0 < K; k0 += 32) {
        float4 wa0 = ra0, wa1 = ra1, wb0 = rb0, wb1 = rb1;
        if (RELU_A) {
            wa0.x = LRELU(wa0.x); wa0.y = LRELU(wa0.y); wa0.z = LRELU(wa0.z); wa0.w = LRELU(wa0.w);
            wa1.x = LRELU(wa1.x); wa1.y = LRELU(wa1.y); wa1.z = LRELU(wa1.z); wa1.w = LRELU(wa1.w);
        }
        sm.As[lk + 0][lm] = wa0.x; sm.As[lk + 1][lm] = wa0.y;
        sm.As[lk + 2][lm] = wa0.z; sm.As[lk + 3][lm] = wa0.w;
        sm.As[lk + 4][lm] = wa1.x; sm.As[lk + 5][lm] = wa1.y;
        sm.As[lk + 6][lm] = wa1.z; sm.As[lk + 7][lm] = wa1.w;
        *(float4*)&sm.Bs[kb][nb]     = wb0;
        *(float4*)&sm.Bs[kb][nb + 4] = wb1;
        __syncthreads();
        if (k0 + 32 < K) {
            if (aValid) {
                ra0 = *(const float4*)(aPtr + k0 + 32);
                ra1 = *(const float4*)(aPtr + k0 + 36);
            }
            rb0 = *(const float4*)(bPtr + (size_t)(k0 + 32) * N);
            rb1 = *(const float4*)(bPtr + (size_t)(k0 + 32) * N + 4);
        }
#pragma unroll
        for (int kk = 0; kk < 32; kk++) {
            float av[4], bv[4];
#pragma unroll
            for (int i = 0; i < 4; i++) av[i] = sm.As[kk][ty * 4 + i];
#pragma unroll
            for (int j = 0; j < 4; j++) bv[j] = sm.Bs[kk][tx * 4 + j];
#pragma unroll
            for (int i = 0; i < 4; i++)
#pragma unroll
                for (int j = 0; j < 4; j++) acc[i][j] += av[i] * bv[j];
        }
        __syncthreads();
    }
#pragma unroll
    for (int i = 0; i < 4; i++) {
        int r = bm + ty * 4 + i;
        if (r < M) {
            float4 v = make_float4(acc[i][0], acc[i][1], acc[i][2], acc[i][3]);
            if (RELU_C) { v.x = LRELU(v.x); v.y = LRELU(v.y); v.z = LRELU(v.z); v.w = LRELU(v.w); }
            *(float4*)(C + (size_t)r * N + bn + tx * 4) = v;
        }
    }
}

// ---------------------------------------------------------------------------
// 128x128-tile GEMM, 8x8 per thread, float4 LDS reads. K % 16 == 0.
template <bool RELU_A>
__device__ __forceinline__ void gemm128_body(Gemm128Smem& sm, int bx, int by,
                                             const float* __restrict__ A,
                                             const float* __restrict__ B,
                                             float* __restrict__ C,
                                             int M, int N, int K) {
    const int bm = bx * 128, bn = by * 128;
    const int tid = threadIdx.x;
    const int tx = tid & 15, ty = tid >> 4;
    const int am = tid >> 1, ak = (tid & 1) * 8;    // A-slab: 128 rows x 16 k
    const int bk = tid >> 4, bn8 = (tid & 15) * 8;  // B-slab: 16 k x 128 cols
    const bool aValid = (bm + am) < M;
    const float* aPtr = A + (size_t)(bm + am) * K + ak;
    const float* bPtr = B + (size_t)bk * N + bn + bn8;
    float4 ra0 = make_float4(0.f, 0.f, 0.f, 0.f), ra1 = ra0, rb0, rb1;
    if (aValid) { ra0 = *(const float4*)aPtr; ra1 = *(const float4*)(aPtr + 4); }
    rb0 = *(const float4*)bPtr;
    rb1 = *(const float4*)(bPtr + 4);
    float acc[8][8] = {};
    for (int k0 = 0; k0 < K; k0 += 16) {
        float a8[8] = { ra0.x, ra0.y, ra0.z, ra0.w, ra1.x, ra1.y, ra1.z, ra1.w };
        if (RELU_A) {
#pragma unroll
            for (int j = 0; j < 8; j++) a8[j] = LRELU(a8[j]);
        }
#pragma unroll
        for (int j = 0; j < 8; j++) sm.As[ak + j][am] = a8[j];
        *(float4*)&sm.Bs[bk][bn8]     = rb0;
        *(float4*)&sm.Bs[bk][bn8 + 4] = rb1;
        __syncthreads();
        if (k0 + 16 < K) {
            if (aValid) {
                ra0 = *(const float4*)(aPtr + k0 + 16);
                ra1 = *(const float4*)(aPtr + k0 + 20);
            }
            rb0 = *(const float4*)(bPtr + (size_t)(k0 + 16) * N);
            rb1 = *(const float4*)(bPtr + (size_t)(k0 + 16) * N + 4);
        }
#pragma unroll
        for (int kk = 0; kk < 16; kk++) {
            float4 a0 = *(const float4*)&sm.As[kk][ty * 8];
            float4 a1 = *(const float4*)&sm.As[kk][ty * 8 + 4];
            float4 b0 = *(const float4*)&sm.Bs[kk][tx * 8];
            float4 b1 = *(const float4*)&sm.Bs[kk][tx * 8 + 4];
            float av[8] = { a0.x, a0.y, a0.z, a0.w, a1.x, a1.y, a1.z, a1.w };
            float bv[8] = { b0.x, b0.y, b0.z, b0.w, b1.x, b1.y, b1.z, b1.w };
#pragma unroll
            for (int i = 0; i < 8; i++)
#pragma unroll
                for (int j = 0; j < 8; j++) acc[i][j] += av[i] * bv[j];
        }
        __syncthreads();
    }
#pragma unroll
    for (int i = 0; i < 8; i++) {
        int r = bm + ty * 8 + i;
        if (r < M) {
            float4 v0 = make_float4(acc[i][0], acc[i][1], acc[i][2], acc[i][3]);
            float4 v1 = make_float4(acc[i][4], acc[i][5], acc[i][6], acc[i][7]);
            *(float4*)(C + (size_t)r * N + bn + tx * 8)     = v0;
            *(float4*)(C + (size_t)r * N + bn + tx * 8 + 4) = v1;
        }
    }
}

// ---------------------------------------------------------------------------
__device__ __forceinline__ void csr_body(CsrSmem& sm, const float* __restrict__ adj,
                                         int* __restrict__ cols,
                                         int* __restrict__ rowcnt, int row) {
    if (threadIdx.x == 0) sm.scnt = 0;
    __syncthreads();
    const float4* rp = (const float4*)(adj + (size_t)row * NDA);
    for (int i = threadIdx.x; i < NDA / 4; i += 256) {
        float4 v = rp[i];
        if (v.x != 0.f) { int s = atomicAdd(&sm.scnt, 1); if (s < CAP) cols[row * CAP + s] = 4 * i; }
        if (v.y != 0.f) { int s = atomicAdd(&sm.scnt, 1); if (s < CAP) cols[row * CAP + s] = 4 * i + 1; }
        if (v.z != 0.f) { int s = atomicAdd(&sm.scnt, 1); if (s < CAP) cols[row * CAP + s] = 4 * i + 2; }
        if (v.w != 0.f) { int s = atomicAdd(&sm.scnt, 1); if (s < CAP) cols[row * CAP + s] = 4 * i + 3; }
    }
    __syncthreads();
    if (threadIdx.x == 0) rowcnt[row] = min(sm.scnt, CAP);
}

// ---------------------------------------------------------------------------
// SpMM body, wave-per-neighbor float4 gather: lane l owns d = 4l..4l+3; wave w
// takes neighbors w, w+4, ... with two rows in flight. Partials combined in LDS.
__device__ __forceinline__ void spmm_body(SpmmSmem& sm, const int* __restrict__ cols,
                                          const int* __restrict__ rowcnt,
                                          const float* __restrict__ X,
                                          float* __restrict__ out1,
                                          float* __restrict__ out2, int row) {
    int t = threadIdx.x;
    int w = t >> 6, lane = t & 63;
    int cnt = rowcnt[row];
    if (t < cnt) sm.sc[t] = cols[row * CAP + t];
    __syncthreads();
    float4 acc = make_float4(0.f, 0.f, 0.f, 0.f);
    int k = w;
    for (; k + 4 < cnt; k += 8) {
        const float4* x0 = (const float4*)(X + (size_t)sm.sc[k] * D);
        const float4* x1 = (const float4*)(X + (size_t)sm.sc[k + 4] * D);
        float4 v0 = x0[lane];
        float4 v1 = x1[lane];
        acc.x += v0.x + v1.x; acc.y += v0.y + v1.y;
        acc.z += v0.z + v1.z; acc.w += v0.w + v1.w;
    }
    for (; k < cnt; k += 4) {
        const float4* x0 = (const float4*)(X + (size_t)sm.sc[k] * D);
        float4 v0 = x0[lane];
        acc.x += v0.x; acc.y += v0.y; acc.z += v0.z; acc.w += v0.w;
    }
    *(float4*)&sm.part[w][lane * 4] = acc;
    __syncthreads();
    float s = sm.part[0][t] + sm.part[1][t] + sm.part[2][t] + sm.part[3][t];
    float v = LRELU(s);
    out1[(size_t)row * D + t] = v;
    if (out2) out2[(size_t)row * D + t] = LRELU(v);
}

// ---------------------------------------------------------------------------
// Cross body: QK-phase wave-per-candidate (coalesced 1KB row load + shuffle
// reduce), PV-phase wave-strided float4 accumulation.
__device__ __forceinline__ void cross_body(CrossSmem& sm, const float* __restrict__ q,
                                           const float* __restrict__ da,
                                           const int* __restrict__ cand,
                                           float* __restrict__ hpart,
                                           int r, int qr) {
    int t = threadIdx.x;
    int w = t >> 6, lane = t & 63;
    float qv = q[r * D + t];
    sm.qs[t] = qv;
    sm.sci[t] = cand[qr * 256 + t];
    float p = wave_red64(qv * qv);
    if (lane == 0) sm.red[w] = p;
    __syncthreads();
    if (t == 0) sm.sqn = fmaxf(sqrtf(sm.red[0] + sm.red[1] + sm.red[2] + sm.red[3]), 1e-12f);
    __syncthreads();
    float qn = sm.sqn;
    float4 qv4 = *(const float4*)&sm.qs[lane * 4];
    // cosine weights: wave w handles candidates [w*64, w*64+64)
    for (int c = w * 64; c < w * 64 + 64; c++) {
        const float4* rp = (const float4*)(da + (size_t)sm.sci[c] * D);
        float4 v = rp[lane];
        float dp = qv4.x * v.x + qv4.y * v.y + qv4.z * v.z + qv4.w * v.w;
        float sq = v.x * v.x + v.y * v.y + v.z * v.z + v.w * v.w;
#pragma unroll
        for (int o = 32; o; o >>= 1) { dp += __shfl_down(dp, o); sq += __shfl_down(sq, o); }
        if (lane == 0) sm.cmw[c] = dp / (qn * fmaxf(sqrtf(sq), 1e-12f));
    }
    __syncthreads();
    // PV: wave-strided weighted sum, two rows in flight
    float4 acc = make_float4(0.f, 0.f, 0.f, 0.f);
    for (int c = w; c < 256; c += 8) {
        float w0 = sm.cmw[c], w1 = sm.cmw[c + 4];
        const float4* p0 = (const float4*)(da + (size_t)sm.sci[c] * D);
        const float4* p1 = (const float4*)(da + (size_t)sm.sci[c + 4] * D);
        float4 v0 = p0[lane];
        float4 v1 = p1[lane];
        acc.x += w0 * v0.x + w1 * v1.x;
        acc.y += w0 * v0.y + w1 * v1.y;
        acc.z += w0 * v0.z + w1 * v1.z;
        acc.w += w0 * v0.w + w1 * v1.w;
    }
    *(float4*)&sm.part[w][lane * 4] = acc;
    __syncthreads();
    float hs = sm.part[0][t] + sm.part[1][t] + sm.part[2][t] + sm.part[3][t];
    hpart[((size_t)qr * NQ + r) * D + t] = hs;
}

// ---------------------------------------------------------------------------
// Stage 0: [X1 gemm128 | Xq gemm64 | CSR build]
__global__ __launch_bounds__(256) void stage0_kernel(const float* __restrict__ adj,
                                                     int* __restrict__ cols,
                                                     int* __restrict__ rowcnt,
                                                     const float* __restrict__ Fda,
                                                     const float* __restrict__ W1da,
                                                     float* __restrict__ X1,
                                                     const float* __restrict__ Fq,
                                                     const float* __restrict__ W1q,
                                                     float* __restrict__ Xq) {
    __shared__ union { Gemm128Smem h; GemmSmem g; CsrSmem z; } sm;
    int bid = blockIdx.x;
    if (bid < NB128) {
        gemm128_body<false>(sm.h, bid >> 1, bid & 1, Fda, W1da, X1, NDA, D, DIN);
    } else if (bid < NB128 + 4) {
        gemm_body<false, false>(sm.g, 0, bid - NB128, Fq, W1q, Xq, NQ, D, DIN);
    } else {
        csr_body(sm.z, adj, cols, rowcnt, bid - (NB128 + 4));
    }
}

// [q-gemm (Qadj @ xq, lrelu) | spmm over all target rows]
__global__ __launch_bounds__(256) void stage_sg_kernel(const int* __restrict__ cols,
                                                       const int* __restrict__ rowcnt,
                                                       const float* __restrict__ X,
                                                       float* __restrict__ out1,
                                                       float* __restrict__ out2,
                                                       const float* __restrict__ Aq,
                                                       const float* __restrict__ Bq,
                                                       float* __restrict__ Cq) {
    __shared__ union { GemmSmem g; SpmmSmem s; } sm;
    int bid = blockIdx.x;
    if (bid < 4) {
        gemm_body<false, true>(sm.g, 0, bid, Aq, Bq, Cq, NQ, D, NQ);
    } else {
        spmm_body(sm.s, cols, rowcnt, X, out1, out2, bid - 4);
    }
}

// [cross1 | Y2 = lrelu(da1) @ W2da via gemm128]
__global__ __launch_bounds__(256) void mergeA_kernel(const float* __restrict__ q1,
                                                     const float* __restrict__ da1,
                                                     const int* __restrict__ cand,
                                                     float* __restrict__ hpart,
                                                     const float* __restrict__ W2da,
                                                     float* __restrict__ Y2) {
    __shared__ union { CrossSmem c; Gemm128Smem h; } sm;
    int bid = blockIdx.x;
    if (bid < 256) {
        cross_body(sm.c, q1, da1, cand, hpart, bid >> 2, bid & 3);
    } else {
        int t = bid - 256;
        gemm128_body<true>(sm.h, t >> 1, t & 1, da1, W2da, Y2, NDA, D, D);
    }
}

// Standalone cross (layer 2)
__global__ __launch_bounds__(256) void cross_kernel(const float* __restrict__ q,
                                                    const float* __restrict__ da,
                                                    const int* __restrict__ cand,
                                                    float* __restrict__ hpart) {
    __shared__ CrossSmem sm;
    cross_body(sm, q, da, cand, hpart, blockIdx.x, blockIdx.y);
}

// ---------------------------------------------------------------------------
// qfused: attq1 computed straight into LDS (A^T layout), then Zq = aq1 @ W2q.
__global__ __launch_bounds__(256) void qfused_kernel(const float* __restrict__ q,
                                                     const float* __restrict__ hpart,
                                                     const float* __restrict__ W2q,
                                                     float* __restrict__ Zq) {
    __shared__ float aqT[D][65];   // A^T: [k][m], m = query row
    __shared__ float Bs[32][68];
    int d = threadIdx.x;
    float hv[NQ];
    float ss = 0.f;
#pragma unroll
    for (int r = 0; r < NQ; r++) {
        float h = hpart[(size_t)r * D + d]
                + hpart[(size_t)(NQ + r) * D + d]
                + hpart[(size_t)(2 * NQ + r) * D + d]
                + hpart[(size_t)(3 * NQ + r) * D + d];
        hv[r] = h;
        ss += h * h;
    }
    float inv = 1.f / fmaxf(sqrtf(ss), 1e-12f);
#pragma unroll
    for (int r = 0; r < NQ; r++) {
        float v = q[r * D + d] + hv[r] * inv;
        aqT[d][r] = LRELU(v);
    }
    __syncthreads();
    const int bn = blockIdx.x * 64;
    const int tx = d & 15, ty = d >> 4;
    const int kb = d >> 3, nb = (d & 7) * 8;
    float acc[4][4] = {};
    for (int k0 = 0; k0 < D; k0 += 32) {
        float4 b0 = *(const float4*)(W2q + (size_t)(k0 + kb) * D + bn + nb);
        float4 b1 = *(const float4*)(W2q + (size_t)(k0 + kb) * D + bn + nb + 4);
        *(float4*)&Bs[kb][nb]     = b0;
        *(float4*)&Bs[kb][nb + 4] = b1;
        __syncthreads();
#pragma unroll
        for (int kk = 0; kk < 32; kk++) {
            float av[4], bv[4];
#pragma unroll
            for (int i = 0; i < 4; i++) av[i] = aqT[k0 + kk][ty * 4 + i];
#pragma unroll
            for (int j = 0; j < 4; j++) bv[j] = Bs[kk][tx * 4 + j];
#pragma unroll
            for (int i = 0; i < 4; i++)
#pragma unroll
                for (int j = 0; j < 4; j++) acc[i][j] += av[i] * bv[j];
        }
        __syncthreads();
    }
#pragma unroll
    for (int i = 0; i < 4; i++) {
        float4 v = make_float4(acc[i][0], acc[i][1], acc[i][2], acc[i][3]);
        *(float4*)(Zq + (size_t)(ty * 4 + i) * D + bn + tx * 4) = v;
    }
}

// ---------------------------------------------------------------------------
// attq (4 blocks, 64 columns each): att_q2 = lrelu(q + h/colnorm(h)), emb = col
// means. Block 0 thread 0 also zero-inits the scalar accumulators.
__global__ __launch_bounds__(256) void attq4_kernel(const float* __restrict__ q,
                                                    const float* __restrict__ hpart,
                                                    float* __restrict__ attq,
                                                    float* __restrict__ emb,
                                                    float* __restrict__ cnt,
                                                    double* __restrict__ tot,
                                                    double* __restrict__ tr) {
    __shared__ Attq4Smem sm;
    int b = blockIdx.x, t = threadIdx.x;
    int lc = t & 63, rq = t >> 6;
    int c = b * 64 + lc;
    if (b == 0 && t == 0) { *cnt = 0.f; *tot = 0.0; *tr = 0.0; }
    float ss = 0.f;
#pragma unroll
    for (int rr = 0; rr < 16; rr++) {
        int r = rq * 16 + rr;
        float h = hpart[(size_t)r * D + c]
                + hpart[(size_t)(NQ + r) * D + c]
                + hpart[(size_t)(2 * NQ + r) * D + c]
                + hpart[(size_t)(3 * NQ + r) * D + c];
        sm.hbuf[r][lc] = h;
        ss += h * h;
    }
    sm.red[rq][lc] = ss;
    __syncthreads();
    if (rq == 0) {
        float s = sm.red[0][lc] + sm.red[1][lc] + sm.red[2][lc] + sm.red[3][lc];
        sm.invs[lc] = 1.f / fmaxf(sqrtf(s), 1e-12f);
    }
    __syncthreads();
    float inv = sm.invs[lc];
    float es = 0.f;
#pragma unroll
    for (int rr = 0; rr < 16; rr++) {
        int r = rq * 16 + rr;
        float v = q[r * D + c] + sm.hbuf[r][lc] * inv;
        v = LRELU(v);
        attq[r * D + c] = v;
        es += v;
    }
    __syncthreads();   // red[] reuse
    sm.red[rq][lc] = es;
    __syncthreads();
    if (rq == 0) {
        float e = (sm.red[0][lc] + sm.red[1][lc] + sm.red[2][lc] + sm.red[3][lc]) * (1.f / (float)NQ);
        emb[c] = e;
    }
}

// ---------------------------------------------------------------------------
// end[i] = (a_i . emb) / max(|a_i|*|emb|, 1e-8); embn recomputed in-block.
__global__ __launch_bounds__(256) void end_kernel(const float* __restrict__ A,
                                                  const float* __restrict__ emb,
                                                  const float* __restrict__ thr_p,
                                                  float* __restrict__ endv,
                                                  float* __restrict__ m,
                                                  float* __restrict__ cnt) {
    __shared__ EndSmem sm;
    int d = threadIdx.x;
    float ev = emb[d];
    sm.se[d] = ev;
    if (d == 0) sm.scnt = 0.f;
    int w = d >> 6, lane = d & 63;
    float pe = wave_red64(ev * ev);
    if (lane == 0) sm.red[w] = pe;
    __syncthreads();
    float embn = sqrtf(sm.red[0] + sm.red[1] + sm.red[2] + sm.red[3]);
    float thr = *thr_p;
    int row = blockIdx.x * 4 + w;
    const float* ar = A + (size_t)row * D;
    float num = 0.f, sq = 0.f;
#pragma unroll
    for (int s = 0; s < 4; s++) {
        float v = ar[lane + 64 * s];
        num += v * sm.se[lane + 64 * s];
        sq += v * v;
    }
#pragma unroll
    for (int o = 32; o; o >>= 1) { num += __shfl_down(num, o); sq += __shfl_down(sq, o); }
    if (lane == 0) {
        float den = fmaxf(sqrtf(sq) * embn, 1e-8f);
        float e = num / den;
        endv[row] = e;
        float mv = e > thr ? 1.f : 0.f;
        m[row] = mv;
        if (mv != 0.f) atomicAdd(&sm.scnt, 1.f);
    }
    __syncthreads();
    if (d == 0 && sm.scnt != 0.f) atomicAdd(cnt, sm.scnt);
}

// ---------------------------------------------------------------------------
// G partials, 128x128 tiles, 8x8/thread. grid (4 tiles, NCHUNK chunks).
__global__ __launch_bounds__(256) void Gpart_kernel(const float* __restrict__ A,
                                                    const float* __restrict__ m,
                                                    float* __restrict__ Gp) {
    __shared__ Gemm128Smem sm;
    int ti = blockIdx.x >> 1, tj = blockIdx.x & 1;
    int base = blockIdx.y * GCHUNK;
    int tid = threadIdx.x;
    int tx = tid & 15, ty = tid >> 4;
    int sr = tid >> 4, sc8 = (tid & 15) * 8;
    float acc[8][8] = {};
    for (int g0 = 0; g0 < GCHUNK; g0 += 16) {
        int r = base + g0 + sr;
        float4 va0 = make_float4(0.f, 0.f, 0.f, 0.f), va1 = va0, vb0 = va0, vb1 = va0;
        float mv = 0.f;
        if (r < NDA) {
            mv = m[r];
            const float* ar = A + (size_t)r * D;
            va0 = *(const float4*)(ar + ti * 128 + sc8);
            va1 = *(const float4*)(ar + ti * 128 + sc8 + 4);
            vb0 = *(const float4*)(ar + tj * 128 + sc8);
            vb1 = *(const float4*)(ar + tj * 128 + sc8 + 4);
        }
        va0.x *= mv; va0.y *= mv; va0.z *= mv; va0.w *= mv;
        va1.x *= mv; va1.y *= mv; va1.z *= mv; va1.w *= mv;
        *(float4*)&sm.As[sr][sc8]     = va0;
        *(float4*)&sm.As[sr][sc8 + 4] = va1;
        *(float4*)&sm.Bs[sr][sc8]     = vb0;
        *(float4*)&sm.Bs[sr][sc8 + 4] = vb1;
        __syncthreads();
#pragma unroll
        for (int kk = 0; kk < 16; kk++) {
            float4 a0 = *(const float4*)&sm.As[kk][ty * 8];
            float4 a1 = *(const float4*)&sm.As[kk][ty * 8 + 4];
            float4 b0 = *(const float4*)&sm.Bs[kk][tx * 8];
            float4 b1 = *(const float4*)&sm.Bs[kk][tx * 8 + 4];
            float av[8] = { a0.x, a0.y, a0.z, a0.w, a1.x, a1.y, a1.z, a1.w };
            float bv[8] = { b0.x, b0.y, b0.z, b0.w, b1.x, b1.y, b1.z, b1.w };
#pragma unroll
            for (int i = 0; i < 8; i++)
#pragma unroll
                for (int j = 0; j < 8; j++) acc[i][j] += av[i] * bv[j];
        }
        __syncthreads();
    }
    float* gp = Gp + (size_t)blockIdx.y * D * D;
#pragma unroll
    for (int i = 0; i < 8; i++) {
        int gi = ti * 128 + ty * 8 + i;
        float4 v0 = make_float4(acc[i][0], acc[i][1], acc[i][2], acc[i][3]);
        float4 v1 = make_float4(acc[i][4], acc[i][5], acc[i][6], acc[i][7]);
        *(float4*)(gp + (size_t)gi * D + tj * 128 + tx * 8)     = v0;
        *(float4*)(gp + (size_t)gi * D + tj * 128 + tx * 8 + 4) = v1;
    }
}

// Reduce the NCHUNK partials into G. grid D*D/256 blocks.
__global__ __launch_bounds__(256) void Gred_kernel(const float* __restrict__ Gp,
                                                   float* __restrict__ G) {
    int idx = blockIdx.x * 256 + threadIdx.x;
    float s = 0.f;
#pragma unroll
    for (int c = 0; c < NCHUNK; c++) s += Gp[(size_t)c * D * D + idx];
    G[idx] = s;
}

// H = att_da2 @ G  (gemm128)
__global__ __launch_bounds__(256) void gemmH_kernel(const float* __restrict__ A,
                                                    const float* __restrict__ B,
                                                    float* __restrict__ C) {
    __shared__ Gemm128Smem sm;
    gemm128_body<false>(sm, blockIdx.x >> 1, blockIdx.x & 1, A, B, C, NDA, D, D);
}

// ---------------------------------------------------------------------------
// Final reduction per masked row i:
//   compact masked neighbors into LDS, wave-per-neighbor float4 gather,
//   then num = a_i.s, den2 = a_i.H_i, self = a_i.a_i in one reduction pass.
__global__ __launch_bounds__(256) void final_kernel(const int* __restrict__ cols,
                                                    const int* __restrict__ rowcnt,
                                                    const float* __restrict__ m,
                                                    const float* __restrict__ A,
                                                    const float* __restrict__ H,
                                                    double* __restrict__ total,
                                                    double* __restrict__ tr) {
    int i = blockIdx.x;
    if (m[i] == 0.f) return;
    __shared__ FinalSmem sm;
    int t = threadIdx.x;
    int w = t >> 6, lane = t & 63;
    int cnt = rowcnt[i];
    if (t == 0) { sm.n = 0; sm.sdiag = 0; }
    __syncthreads();
    if (t < cnt) {
        int j = cols[i * CAP + t];
        if (m[j] != 0.f) {
            int s = atomicAdd(&sm.n, 1);
            sm.sc[s] = j;
            if (j == i) sm.sdiag = 1;
        }
    }
    __syncthreads();
    int n = sm.n;
    float4 acc = make_float4(0.f, 0.f, 0.f, 0.f);
    int k = w;
    for (; k + 4 < n; k += 8) {
        const float4* x0 = (const float4*)(A + (size_t)sm.sc[k] * D);
        const float4* x1 = (const float4*)(A + (size_t)sm.sc[k + 4] * D);
        float4 v0 = x0[lane];
        float4 v1 = x1[lane];
        acc.x += v0.x + v1.x; acc.y += v0.y + v1.y;
        acc.z += v0.z + v1.z; acc.w += v0.w + v1.w;
    }
    for (; k < n; k += 4) {
        const float4* x0 = (const float4*)(A + (size_t)sm.sc[k] * D);
        float4 v0 = x0[lane];
        acc.x += v0.x; acc.y += v0.y; acc.z += v0.z; acc.w += v0.w;
    }
    *(float4*)&sm.part[w][lane * 4] = acc;
    __syncthreads();
    float av = A[(size_t)i * D + t];
    float hv = H[(size_t)i * D + t];
    float sd = sm.part[0][t] + sm.part[1][t] + sm.part[2][t] + sm.part[3][t];
    float p1 = av * sd, p2 = av * hv, p3 = av * av;
#pragma unroll
    for (int o = 32; o; o >>= 1) {
        p1 += __shfl_down(p1, o);
        p2 += __shfl_down(p2, o);
        p3 += __shfl_down(p3, o);
    }
    if (lane == 0) { sm.r1[w] = p1; sm.r2[w] = p2; sm.r3[w] = p3; }
    __syncthreads();
    if (t == 0) {
        float num  = sm.r1[0] + sm.r1[1] + sm.r1[2] + sm.r1[3];
        float den2 = sm.r2[0] + sm.r2[1] + sm.r2[2] + sm.r2[3];
        float self = sm.r3[0] + sm.r3[1] + sm.r3[2] + sm.r3[3];
        float denom = fmaxf(sqrtf(den2), 1e-12f);
        double inv = 1.0 / (double)denom;
        if (num != 0.f) atomicAdd(total, (double)num * inv);
        if (sm.sdiag) atomicAdd(tr, (double)self * inv);
    }
}

// ---------------------------------------------------------------------------
__global__ void scalars_kernel(const float* __restrict__ cnt,
                               const double* __restrict__ total,
                               const double* __restrict__ tr,
                               float* __restrict__ out) {
    float c = *cnt;
    float T = (float)*total;
    float R = (float)*tr;
    bool has = c > 0.f;
    out[0] = has ? (T / fmaxf(c, 1.f)) : 0.f;                       // pre_avg_degree
    out[1] = has ? (2.f * T / (R * (R - 1.f) + 1e-4f)) : 0.f;       // pre_density
    out[2] = has ? R : 0.f;                                          // pre_avg_nodes
}

// ---------------------------------------------------------------------------
extern "C" void kernel_launch(void* const* d_in, const int* in_sizes, int n_in,
                              void* d_out, int out_size, void* d_ws, size_t ws_size,
                              hipStream_t stream) {
    (void)in_sizes; (void)n_in; (void)out_size; (void)ws_size;
    const float* adj  = (const float*)d_in[0];
    const float* Fda  = (const float*)d_in[1];
    const float* Qadj = (const float*)d_in[2];
    const float* Fq   = (const float*)d_in[3];
    const int*   cand = (const int*)d_in[4];
    // d_in[5] candidate_adj: unused by the reference
    const float* thr  = (const float*)d_in[6];
    const float* W1da = (const float*)d_in[7];
    const float* W1q  = (const float*)d_in[8];
    const float* W2da = (const float*)d_in[9];
    const float* W2q  = (const float*)d_in[10];

    float* out = (float*)d_out;
    float* o_end    = out;                           // [10000]
    float* o_attda2 = out + NDA;                     // [10000,256]
    float* o_attq2  = out + NDA + (size_t)NDA * D;   // [64,256]
    float* o_sc     = o_attq2 + NQ * D;              // [3] scalars

    char* w = (char*)d_ws;
    size_t off = 0;
    auto alloc = [&](size_t b) { size_t r = off; off += (b + 255) & ~(size_t)255; return r; };
    float* bufA = (float*)(w + alloc((size_t)NDA * D * 4));   // X1 -> Y2
    float* bufB = (float*)(w + alloc((size_t)NDA * D * 4));   // da1 -> H
    float* bufC = (float*)(w + alloc((size_t)NDA * D * 4));   // da2
    int* colsb   = (int*)(w + alloc((size_t)NDA * CAP * 4));
    int* rowcntb = (int*)(w + alloc((size_t)NDA * 4));
    float* mbuf  = (float*)(w + alloc((size_t)NDA * 4));
    float* Gb    = (float*)(w + alloc((size_t)D * D * 4));            // reduced G
    float* Gp    = (float*)(w + alloc((size_t)NCHUNK * D * D * 4));   // G partials
    char* zbase = w + alloc(256);                                     // scalar accumulators
    float* cntb  = (float*)zbase;
    double* totb = (double*)(zbase + 8);
    double* trb  = (double*)(zbase + 16);
    float* xq   = (float*)(w + alloc((size_t)NQ * D * 4));    // Xq -> Zq
    float* q1b  = (float*)(w + alloc((size_t)NQ * D * 4));
    float* q2b  = (float*)(w + alloc((size_t)NQ * D * 4));
    float* hpart = (float*)(w + alloc((size_t)4 * NQ * D * 4));
    float* embb = (float*)(w + alloc((size_t)(D + 1) * 4));

    // Layer 1
    stage0_kernel<<<NB128 + 4 + NDA, 256, 0, stream>>>(adj, colsb, rowcntb,
                                                       Fda, W1da, bufA, Fq, W1q, xq);
    stage_sg_kernel<<<NDA + 4, 256, 0, stream>>>(colsb, rowcntb, bufA, bufB, (float*)nullptr,
                                                 Qadj, xq, q1b);                   // q1 | da1
    mergeA_kernel<<<256 + NB128, 256, 0, stream>>>(q1b, bufB, cand, hpart, W2da, bufA); // cross1 | Y2
    qfused_kernel<<<4, 256, 0, stream>>>(q1b, hpart, W2q, xq);                     // att_q1 -> Zq
    // Layer 2
    stage_sg_kernel<<<NDA + 4, 256, 0, stream>>>(colsb, rowcntb, bufA, bufC, o_attda2,
                                                 Qadj, xq, q2b);                   // q2 | da2
    cross_kernel<<<dim3(NQ, 4), 256, 0, stream>>>(q2b, bufC, cand, hpart);
    attq4_kernel<<<4, 256, 0, stream>>>(q2b, hpart, o_attq2, embb, cntb, totb, trb);
    // Scoring
    end_kernel<<<NDA / 4, 256, 0, stream>>>(o_attda2, embb, thr, o_end, mbuf, cntb);
    Gpart_kernel<<<dim3(4, NCHUNK), 256, 0, stream>>>(o_attda2, mbuf, Gp);
    Gred_kernel<<<D * D / 256, 256, 0, stream>>>(Gp, Gb);
    gemmH_kernel<<<NB128, 256, 0, stream>>>(o_attda2, Gb, bufB);                   // H = A @ G
    final_kernel<<<NDA, 256, 0, stream>>>(colsb, rowcntb, mbuf, o_attda2, bufB, totb, trb);
    scalars_kernel<<<1, 1, 0, stream>>>(cntb, totb, trb, o_sc);
}

// Round 6
// 1077.614 us; speedup vs baseline: 1.6609x; 1.0169x over previous
//
#include <hip/hip_runtime.h>

// Problem constants (fixed by setup_inputs)
constexpr int NDA = 10000;   // target graph nodes
constexpr int NQ  = 64;      // query graph nodes
constexpr int CND = 1024;    // candidate set size
constexpr int DIN = 128;     // input feature dim
constexpr int D   = 256;     // hidden dim
constexpr int CAP = 96;      // max nnz per adjacency row (Poisson(20); P(>96) ~ 0)
constexpr int NB64 = ((NDA + 63) / 64) * (D / 64);   // 157*4 = 628 blocks for 10000x256 gemm
constexpr int GCHUNK = 400;                           // G_kernel: 25 chunks x 400 rows

#define LRELU(x) ((x) >= 0.f ? (x) : 0.01f * (x))

__device__ __forceinline__ float wave_red64(float v) {
#pragma unroll
    for (int o = 32; o; o >>= 1) v += __shfl_down(v, o);
    return v;
}

// ---------------------------------------------------------------------------
// Per-stage shared-memory structs.
struct GemmSmem  { float As[32][65]; float Bs[32][68]; };   // 64x64 tile gemm (~17 KB)
struct CrossSmem { float qs[D]; float cmw[256]; int sci[256]; float red[4]; float sqn; float part[4][256]; };
struct SpmmSmem  { int sc[CAP]; float part[4][256]; };
struct CsrSmem   { int scnt; };
struct EndSmem   { float se[D]; float scnt; float red[4]; };
struct FinalSmem { int sc[CAP]; float part[4][256]; int n; int sdiag; float r1[4], r2[4], r3[4]; };
struct Attq4Smem { float hbuf[64][65]; float red[4][64]; float invs[64]; };

// ---------------------------------------------------------------------------
// 64x64-tile GEMM: 4x4/thread, K%32==0, register prefetch. ~80 VGPR -> keeps
// merged-dispatch gather bodies at decent wave occupancy (the round-5 lesson).
template <bool RELU_A, bool RELU_C>
__device__ __forceinline__ void gemm_body(GemmSmem& sm, int bx, int by,
                                          const float* __restrict__ A,
                                          const float* __restrict__ B,
                                          float* __restrict__ C,
                                          int M, int N, int K) {
    const int bm = bx * 64, bn = by * 64;
    const int tid = threadIdx.x;
    const int tx = tid & 15, ty = tid >> 4;
    const int lm = tid >> 2, lk = (tid & 3) * 8;
    const int kb = tid >> 3, nb = (tid & 7) * 8;
    const bool aValid = (bm + lm) < M;
    const float* aPtr = A + (size_t)(bm + lm) * K + lk;
    const float* bPtr = B + (size_t)kb * N + bn + nb;
    float4 ra0 = make_float4(0.f, 0.f, 0.f, 0.f), ra1 = ra0, rb0, rb1;
    if (aValid) { ra0 = *(const float4*)aPtr; ra1 = *(const float4*)(aPtr + 4); }
    rb0 = *(const float4*)bPtr;
    rb1 = *(const float4*)(bPtr + 4);
    float acc[4][4] = {};
    for (int k0 = 0; k0 < K; k0 += 32) {
        float4 wa0 = ra0, wa1 = ra1, wb0 = rb0, wb1 = rb1;
        if (RELU_A) {
            wa0.x = LRELU(wa0.x); wa0.y = LRELU(wa0.y); wa0.z = LRELU(wa0.z); wa0.w = LRELU(wa0.w);
            wa1.x = LRELU(wa1.x); wa1.y = LRELU(wa1.y); wa1.z = LRELU(wa1.z); wa1.w = LRELU(wa1.w);
        }
        sm.As[lk + 0][lm] = wa0.x; sm.As[lk + 1][lm] = wa0.y;
        sm.As[lk + 2][lm] = wa0.z; sm.As[lk + 3][lm] = wa0.w;
        sm.As[lk + 4][lm] = wa1.x; sm.As[lk + 5][lm] = wa1.y;
        sm.As[lk + 6][lm] = wa1.z; sm.As[lk + 7][lm] = wa1.w;
        *(float4*)&sm.Bs[kb][nb]     = wb0;
        *(float4*)&sm.Bs[kb][nb + 4] = wb1;
        __syncthreads();
        if (k0 + 32 < K) {
            if (aValid) {
                ra0 = *(const float4*)(aPtr + k0 + 32);
                ra1 = *(const float4*)(aPtr + k0 + 36);
            }
            rb0 = *(const float4*)(bPtr + (size_t)(k0 + 32) * N);
            rb1 = *(const float4*)(bPtr + (size_t)(k0 + 32) * N + 4);
        }
#pragma unroll
        for (int kk = 0; kk < 32; kk++) {
            float av[4], bv[4];
#pragma unroll
            for (int i = 0; i < 4; i++) av[i] = sm.As[kk][ty * 4 + i];
#pragma unroll
            for (int j = 0; j < 4; j++) bv[j] = sm.Bs[kk][tx * 4 + j];
#pragma unroll
            for (int i = 0; i < 4; i++)
#pragma unroll
                for (int j = 0; j < 4; j++) acc[i][j] += av[i] * bv[j];
        }
        __syncthreads();
    }
#pragma unroll
    for (int i = 0; i < 4; i++) {
        int r = bm + ty * 4 + i;
        if (r < M) {
            float4 v = make_float4(acc[i][0], acc[i][1], acc[i][2], acc[i][3]);
            if (RELU_C) { v.x = LRELU(v.x); v.y = LRELU(v.y); v.z = LRELU(v.z); v.w = LRELU(v.w); }
            *(float4*)(C + (size_t)r * N + bn + tx * 4) = v;
        }
    }
}

// ---------------------------------------------------------------------------
__device__ __forceinline__ void csr_body(CsrSmem& sm, const float* __restrict__ adj,
                                         int* __restrict__ cols,
                                         int* __restrict__ rowcnt, int row) {
    if (threadIdx.x == 0) sm.scnt = 0;
    __syncthreads();
    const float4* rp = (const float4*)(adj + (size_t)row * NDA);
    for (int i = threadIdx.x; i < NDA / 4; i += 256) {
        float4 v = rp[i];
        if (v.x != 0.f) { int s = atomicAdd(&sm.scnt, 1); if (s < CAP) cols[row * CAP + s] = 4 * i; }
        if (v.y != 0.f) { int s = atomicAdd(&sm.scnt, 1); if (s < CAP) cols[row * CAP + s] = 4 * i + 1; }
        if (v.z != 0.f) { int s = atomicAdd(&sm.scnt, 1); if (s < CAP) cols[row * CAP + s] = 4 * i + 2; }
        if (v.w != 0.f) { int s = atomicAdd(&sm.scnt, 1); if (s < CAP) cols[row * CAP + s] = 4 * i + 3; }
    }
    __syncthreads();
    if (threadIdx.x == 0) rowcnt[row] = min(sm.scnt, CAP);
}

// ---------------------------------------------------------------------------
// SpMM, wave-per-neighbor float4 gather: lane l owns d = 4l..4l+3; wave w takes
// neighbors w, w+4, ... (two rows in flight). Partials combined through LDS.
__device__ __forceinline__ void spmm_body(SpmmSmem& sm, const int* __restrict__ cols,
                                          const int* __restrict__ rowcnt,
                                          const float* __restrict__ X,
                                          float* __restrict__ out1,
                                          float* __restrict__ out2, int row) {
    int t = threadIdx.x;
    int w = t >> 6, lane = t & 63;
    int cnt = rowcnt[row];
    if (t < cnt) sm.sc[t] = cols[row * CAP + t];
    __syncthreads();
    float4 acc = make_float4(0.f, 0.f, 0.f, 0.f);
    int k = w;
    for (; k + 4 < cnt; k += 8) {
        const float4* x0 = (const float4*)(X + (size_t)sm.sc[k] * D);
        const float4* x1 = (const float4*)(X + (size_t)sm.sc[k + 4] * D);
        float4 v0 = x0[lane];
        float4 v1 = x1[lane];
        acc.x += v0.x + v1.x; acc.y += v0.y + v1.y;
        acc.z += v0.z + v1.z; acc.w += v0.w + v1.w;
    }
    for (; k < cnt; k += 4) {
        const float4* x0 = (const float4*)(X + (size_t)sm.sc[k] * D);
        float4 v0 = x0[lane];
        acc.x += v0.x; acc.y += v0.y; acc.z += v0.z; acc.w += v0.w;
    }
    *(float4*)&sm.part[w][lane * 4] = acc;
    __syncthreads();
    float s = sm.part[0][t] + sm.part[1][t] + sm.part[2][t] + sm.part[3][t];
    float v = LRELU(s);
    out1[(size_t)row * D + t] = v;
    if (out2) out2[(size_t)row * D + t] = LRELU(v);
}

// ---------------------------------------------------------------------------
// Cross (rownorms+cosmat+hq fused): QK-phase wave-per-candidate (coalesced 1 KB
// row load + shuffle reduce), PV-phase wave-strided float4 accumulation.
__device__ __forceinline__ void cross_body(CrossSmem& sm, const float* __restrict__ q,
                                           const float* __restrict__ da,
                                           const int* __restrict__ cand,
                                           float* __restrict__ hpart,
                                           int r, int qr) {
    int t = threadIdx.x;
    int w = t >> 6, lane = t & 63;
    float qv = q[r * D + t];
    sm.qs[t] = qv;
    sm.sci[t] = cand[qr * 256 + t];
    float p = wave_red64(qv * qv);
    if (lane == 0) sm.red[w] = p;
    __syncthreads();
    if (t == 0) sm.sqn = fmaxf(sqrtf(sm.red[0] + sm.red[1] + sm.red[2] + sm.red[3]), 1e-12f);
    __syncthreads();
    float qn = sm.sqn;
    float4 qv4 = *(const float4*)&sm.qs[lane * 4];
    for (int c = w * 64; c < w * 64 + 64; c++) {
        const float4* rp = (const float4*)(da + (size_t)sm.sci[c] * D);
        float4 v = rp[lane];
        float dp = qv4.x * v.x + qv4.y * v.y + qv4.z * v.z + qv4.w * v.w;
        float sq = v.x * v.x + v.y * v.y + v.z * v.z + v.w * v.w;
#pragma unroll
        for (int o = 32; o; o >>= 1) { dp += __shfl_down(dp, o); sq += __shfl_down(sq, o); }
        if (lane == 0) sm.cmw[c] = dp / (qn * fmaxf(sqrtf(sq), 1e-12f));
    }
    __syncthreads();
    float4 acc = make_float4(0.f, 0.f, 0.f, 0.f);
    for (int c = w; c < 256; c += 8) {
        float w0 = sm.cmw[c], w1 = sm.cmw[c + 4];
        const float4* p0 = (const float4*)(da + (size_t)sm.sci[c] * D);
        const float4* p1 = (const float4*)(da + (size_t)sm.sci[c + 4] * D);
        float4 v0 = p0[lane];
        float4 v1 = p1[lane];
        acc.x += w0 * v0.x + w1 * v1.x;
        acc.y += w0 * v0.y + w1 * v1.y;
        acc.z += w0 * v0.z + w1 * v1.z;
        acc.w += w0 * v0.w + w1 * v1.w;
    }
    *(float4*)&sm.part[w][lane * 4] = acc;
    __syncthreads();
    float hs = sm.part[0][t] + sm.part[1][t] + sm.part[2][t] + sm.part[3][t];
    hpart[((size_t)qr * NQ + r) * D + t] = hs;
}

// ---------------------------------------------------------------------------
// Stage 0: [X1 gemm64 | Xq gemm64 | zero-G | CSR build] — independent work
// co-scheduled; gemm64 keeps kernel VGPR at ~80 so CSR blocks retain occupancy.
__global__ __launch_bounds__(256) void stage0_kernel(const float* __restrict__ adj,
                                                     int* __restrict__ cols,
                                                     int* __restrict__ rowcnt,
                                                     const float* __restrict__ Fda,
                                                     const float* __restrict__ W1da,
                                                     float* __restrict__ X1,
                                                     const float* __restrict__ Fq,
                                                     const float* __restrict__ W1q,
                                                     float* __restrict__ Xq,
                                                     float* __restrict__ G) {
    __shared__ union { GemmSmem g; CsrSmem z; } sm;
    int bid = blockIdx.x;
    if (bid < NB64) {
        gemm_body<false, false>(sm.g, bid >> 2, bid & 3, Fda, W1da, X1, NDA, D, DIN);
    } else if (bid < NB64 + 4) {
        gemm_body<false, false>(sm.g, 0, bid - NB64, Fq, W1q, Xq, NQ, D, DIN);
    } else if (bid < NB64 + 20) {
        int zb = bid - (NB64 + 4);                 // 16 blocks zero G (64K floats)
        float4* g4 = (float4*)G;
        int base = zb * 1024 + threadIdx.x;
#pragma unroll
        for (int k = 0; k < 4; k++)
            g4[base + k * 256] = make_float4(0.f, 0.f, 0.f, 0.f);
    } else {
        csr_body(sm.z, adj, cols, rowcnt, bid - (NB64 + 20));
    }
}

// [q-gemm (Qadj @ xq, lrelu) | spmm over all target rows]
__global__ __launch_bounds__(256) void stage_sg_kernel(const int* __restrict__ cols,
                                                       const int* __restrict__ rowcnt,
                                                       const float* __restrict__ X,
                                                       float* __restrict__ out1,
                                                       float* __restrict__ out2,
                                                       const float* __restrict__ Aq,
                                                       const float* __restrict__ Bq,
                                                       float* __restrict__ Cq) {
    __shared__ union { GemmSmem g; SpmmSmem s; } sm;
    int bid = blockIdx.x;
    if (bid < 4) {
        gemm_body<false, true>(sm.g, 0, bid, Aq, Bq, Cq, NQ, D, NQ);
    } else {
        spmm_body(sm.s, cols, rowcnt, X, out1, out2, bid - 4);
    }
}

// [cross1 | Y2 = lrelu(da1) @ W2da]
__global__ __launch_bounds__(256) void mergeA_kernel(const float* __restrict__ q1,
                                                     const float* __restrict__ da1,
                                                     const int* __restrict__ cand,
                                                     float* __restrict__ hpart,
                                                     const float* __restrict__ W2da,
                                                     float* __restrict__ Y2) {
    __shared__ union { CrossSmem c; GemmSmem g; } sm;
    int bid = blockIdx.x;
    if (bid < 256) {
        cross_body(sm.c, q1, da1, cand, hpart, bid >> 2, bid & 3);
    } else {
        int t = bid - 256;
        gemm_body<true, false>(sm.g, t >> 2, t & 3, da1, W2da, Y2, NDA, D, D);
    }
}

// Standalone cross (layer 2)
__global__ __launch_bounds__(256) void cross_kernel(const float* __restrict__ q,
                                                    const float* __restrict__ da,
                                                    const int* __restrict__ cand,
                                                    float* __restrict__ hpart) {
    __shared__ CrossSmem sm;
    cross_body(sm, q, da, cand, hpart, blockIdx.x, blockIdx.y);
}

// ---------------------------------------------------------------------------
// qfused: attq1 computed straight into LDS (A^T layout), then Zq = aq1 @ W2q.
__global__ __launch_bounds__(256) void qfused_kernel(const float* __restrict__ q,
                                                     const float* __restrict__ hpart,
                                                     const float* __restrict__ W2q,
                                                     float* __restrict__ Zq) {
    __shared__ float aqT[D][65];   // A^T: [k][m], m = query row
    __shared__ float Bs[32][68];
    int d = threadIdx.x;
    float hv[NQ];
    float ss = 0.f;
#pragma unroll
    for (int r = 0; r < NQ; r++) {
        float h = hpart[(size_t)r * D + d]
                + hpart[(size_t)(NQ + r) * D + d]
                + hpart[(size_t)(2 * NQ + r) * D + d]
                + hpart[(size_t)(3 * NQ + r) * D + d];
        hv[r] = h;
        ss += h * h;
    }
    float inv = 1.f / fmaxf(sqrtf(ss), 1e-12f);
#pragma unroll
    for (int r = 0; r < NQ; r++) {
        float v = q[r * D + d] + hv[r] * inv;
        aqT[d][r] = LRELU(v);
    }
    __syncthreads();
    const int bn = blockIdx.x * 64;
    const int tx = d & 15, ty = d >> 4;
    const int kb = d >> 3, nb = (d & 7) * 8;
    float acc[4][4] = {};
    for (int k0 = 0; k0 < D; k0 += 32) {
        float4 b0 = *(const float4*)(W2q + (size_t)(k0 + kb) * D + bn + nb);
        float4 b1 = *(const float4*)(W2q + (size_t)(k0 + kb) * D + bn + nb + 4);
        *(float4*)&Bs[kb][nb]     = b0;
        *(float4*)&Bs[kb][nb + 4] = b1;
        __syncthreads();
#pragma unroll
        for (int kk = 0; kk < 32; kk++) {
            float av[4], bv[4];
#pragma unroll
            for (int i = 0; i < 4; i++) av[i] = aqT[k0 + kk][ty * 4 + i];
#pragma unroll
            for (int j = 0; j < 4; j++) bv[j] = Bs[kk][tx * 4 + j];
#pragma unroll
            for (int i = 0; i < 4; i++)
#pragma unroll
                for (int j = 0; j < 4; j++) acc[i][j] += av[i] * bv[j];
        }
        __syncthreads();
    }
#pragma unroll
    for (int i = 0; i < 4; i++) {
        float4 v = make_float4(acc[i][0], acc[i][1], acc[i][2], acc[i][3]);
        *(float4*)(Zq + (size_t)(ty * 4 + i) * D + bn + tx * 4) = v;
    }
}

// ---------------------------------------------------------------------------
// attq (4 blocks, 64 columns each): att_q2 = lrelu(q + h/colnorm(h)), emb = col
// means. Block 0 thread 0 also zero-inits the scalar accumulators.
__global__ __launch_bounds__(256) void attq4_kernel(const float* __restrict__ q,
                                                    const float* __restrict__ hpart,
                                                    float* __restrict__ attq,
                                                    float* __restrict__ emb,
                                                    float* __restrict__ cnt,
                                                    double* __restrict__ tot,
                                                    double* __restrict__ tr) {
    __shared__ Attq4Smem sm;
    int b = blockIdx.x, t = threadIdx.x;
    int lc = t & 63, rq = t >> 6;
    int c = b * 64 + lc;
    if (b == 0 && t == 0) { *cnt = 0.f; *tot = 0.0; *tr = 0.0; }
    float ss = 0.f;
#pragma unroll
    for (int rr = 0; rr < 16; rr++) {
        int r = rq * 16 + rr;
        float h = hpart[(size_t)r * D + c]
                + hpart[(size_t)(NQ + r) * D + c]
                + hpart[(size_t)(2 * NQ + r) * D + c]
                + hpart[(size_t)(3 * NQ + r) * D + c];
        sm.hbuf[r][lc] = h;
        ss += h * h;
    }
    sm.red[rq][lc] = ss;
    __syncthreads();
    if (rq == 0) {
        float s = sm.red[0][lc] + sm.red[1][lc] + sm.red[2][lc] + sm.red[3][lc];
        sm.invs[lc] = 1.f / fmaxf(sqrtf(s), 1e-12f);
    }
    __syncthreads();
    float inv = sm.invs[lc];
    float es = 0.f;
#pragma unroll
    for (int rr = 0; rr < 16; rr++) {
        int r = rq * 16 + rr;
        float v = q[r * D + c] + sm.hbuf[r][lc] * inv;
        v = LRELU(v);
        attq[r * D + c] = v;
        es += v;
    }
    __syncthreads();   // red[] reuse
    sm.red[rq][lc] = es;
    __syncthreads();
    if (rq == 0) {
        float e = (sm.red[0][lc] + sm.red[1][lc] + sm.red[2][lc] + sm.red[3][lc]) * (1.f / (float)NQ);
        emb[c] = e;
    }
}

// ---------------------------------------------------------------------------
// end[i] = (a_i . emb) / max(|a_i|*|emb|, 1e-8); embn recomputed in-block.
__global__ __launch_bounds__(256) void end_kernel(const float* __restrict__ A,
                                                  const float* __restrict__ emb,
                                                  const float* __restrict__ thr_p,
                                                  float* __restrict__ endv,
                                                  float* __restrict__ m,
                                                  float* __restrict__ cnt) {
    __shared__ EndSmem sm;
    int d = threadIdx.x;
    float ev = emb[d];
    sm.se[d] = ev;
    if (d == 0) sm.scnt = 0.f;
    int w = d >> 6, lane = d & 63;
    float pe = wave_red64(ev * ev);
    if (lane == 0) sm.red[w] = pe;
    __syncthreads();
    float embn = sqrtf(sm.red[0] + sm.red[1] + sm.red[2] + sm.red[3]);
    float thr = *thr_p;
    int row = blockIdx.x * 4 + w;
    const float* ar = A + (size_t)row * D;
    float num = 0.f, sq = 0.f;
#pragma unroll
    for (int s = 0; s < 4; s++) {
        float v = ar[lane + 64 * s];
        num += v * sm.se[lane + 64 * s];
        sq += v * v;
    }
#pragma unroll
    for (int o = 32; o; o >>= 1) { num += __shfl_down(num, o); sq += __shfl_down(sq, o); }
    if (lane == 0) {
        float den = fmaxf(sqrtf(sq) * embn, 1e-8f);
        float e = num / den;
        endv[row] = e;
        float mv = e > thr ? 1.f : 0.f;
        m[row] = mv;
        if (mv != 0.f) atomicAdd(&sm.scnt, 1.f);
    }
    __syncthreads();
    if (d == 0 && sm.scnt != 0.f) atomicAdd(cnt, sm.scnt);
}

// ---------------------------------------------------------------------------
// G = sum_i m_i a_i a_i^T via direct atomics (r1 proved atomics are not a
// bottleneck; saves a reduce dispatch + 8 MB partials round-trip).
// grid (16 tiles, 25 chunks), 4 KB LDS, ~40 VGPR -> high occupancy.
__global__ __launch_bounds__(256) void G_kernel(const float* __restrict__ A,
                                                const float* __restrict__ m,
                                                float* __restrict__ G) {
    __shared__ float SA[8][64], SB[8][64];
    int ti = blockIdx.x >> 2, tj = blockIdx.x & 3;
    int base = blockIdx.y * GCHUNK;
    int tid = threadIdx.x;
    int tx = tid & 15, ty = tid >> 4;
    float acc[4][4] = {};
    for (int g0 = 0; g0 < GCHUNK; g0 += 8) {
        for (int l = tid; l < 512; l += 256) {
            int rr = l >> 6, c = l & 63;
            int r = base + g0 + rr;
            float mv = m[r];
            SA[rr][c] = A[(size_t)r * D + ti * 64 + c] * mv;
            SB[rr][c] = A[(size_t)r * D + tj * 64 + c];
        }
        __syncthreads();
#pragma unroll
        for (int rr = 0; rr < 8; rr++) {
            float av[4], bv[4];
#pragma unroll
            for (int i = 0; i < 4; i++) av[i] = SA[rr][ty * 4 + i];
#pragma unroll
            for (int j = 0; j < 4; j++) bv[j] = SB[rr][tx * 4 + j];
#pragma unroll
            for (int i = 0; i < 4; i++)
#pragma unroll
                for (int j = 0; j < 4; j++) acc[i][j] += av[i] * bv[j];
        }
        __syncthreads();
    }
#pragma unroll
    for (int i = 0; i < 4; i++)
#pragma unroll
        for (int j = 0; j < 4; j++)
            atomicAdd(&G[(ti * 64 + ty * 4 + i) * D + tj * 64 + tx * 4 + j], acc[i][j]);
}

// H = att_da2 @ G  (gemm64, 628 blocks fills the GPU)
__global__ __launch_bounds__(256) void gemmH_kernel(const float* __restrict__ A,
                                                    const float* __restrict__ B,
                                                    float* __restrict__ C) {
    __shared__ GemmSmem sm;
    gemm_body<false, false>(sm, blockIdx.x, blockIdx.y, A, B, C, NDA, D, D);
}

// ---------------------------------------------------------------------------
// Final reduction per masked row i: compact masked neighbors into LDS,
// wave-per-neighbor float4 gather, then num/den2/self in one reduction pass.
__global__ __launch_bounds__(256) void final_kernel(const int* __restrict__ cols,
                                                    const int* __restrict__ rowcnt,
                                                    const float* __restrict__ m,
                                                    const float* __restrict__ A,
                                                    const float* __restrict__ H,
                                                    double* __restrict__ total,
                                                    double* __restrict__ tr) {
    int i = blockIdx.x;
    if (m[i] == 0.f) return;
    __shared__ FinalSmem sm;
    int t = threadIdx.x;
    int w = t >> 6, lane = t & 63;
    int cnt = rowcnt[i];
    if (t == 0) { sm.n = 0; sm.sdiag = 0; }
    __syncthreads();
    if (t < cnt) {
        int j = cols[i * CAP + t];
        if (m[j] != 0.f) {
            int s = atomicAdd(&sm.n, 1);
            sm.sc[s] = j;
            if (j == i) sm.sdiag = 1;
        }
    }
    __syncthreads();
    int n = sm.n;
    float4 acc = make_float4(0.f, 0.f, 0.f, 0.f);
    int k = w;
    for (; k + 4 < n; k += 8) {
        const float4* x0 = (const float4*)(A + (size_t)sm.sc[k] * D);
        const float4* x1 = (const float4*)(A + (size_t)sm.sc[k + 4] * D);
        float4 v0 = x0[lane];
        float4 v1 = x1[lane];
        acc.x += v0.x + v1.x; acc.y += v0.y + v1.y;
        acc.z += v0.z + v1.z; acc.w += v0.w + v1.w;
    }
    for (; k < n; k += 4) {
        const float4* x0 = (const float4*)(A + (size_t)sm.sc[k] * D);
        float4 v0 = x0[lane];
        acc.x += v0.x; acc.y += v0.y; acc.z += v0.z; acc.w += v0.w;
    }
    *(float4*)&sm.part[w][lane * 4] = acc;
    __syncthreads();
    float av = A[(size_t)i * D + t];
    float hv = H[(size_t)i * D + t];
    float sd = sm.part[0][t] + sm.part[1][t] + sm.part[2][t] + sm.part[3][t];
    float p1 = av * sd, p2 = av * hv, p3 = av * av;
#pragma unroll
    for (int o = 32; o; o >>= 1) {
        p1 += __shfl_down(p1, o);
        p2 += __shfl_down(p2, o);
        p3 += __shfl_down(p3, o);
    }
    if (lane == 0) { sm.r1[w] = p1; sm.r2[w] = p2; sm.r3[w] = p3; }
    __syncthreads();
    if (t == 0) {
        float num  = sm.r1[0] + sm.r1[1] + sm.r1[2] + sm.r1[3];
        float den2 = sm.r2[0] + sm.r2[1] + sm.r2[2] + sm.r2[3];
        float self = sm.r3[0] + sm.r3[1] + sm.r3[2] + sm.r3[3];
        float denom = fmaxf(sqrtf(den2), 1e-12f);
        double inv = 1.0 / (double)denom;
        if (num != 0.f) atomicAdd(total, (double)num * inv);
        if (sm.sdiag) atomicAdd(tr, (double)self * inv);
    }
}

// ---------------------------------------------------------------------------
__global__ void scalars_kernel(const float* __restrict__ cnt,
                               const double* __restrict__ total,
                               const double* __restrict__ tr,
                               float* __restrict__ out) {
    float c = *cnt;
    float T = (float)*total;
    float R = (float)*tr;
    bool has = c > 0.f;
    out[0] = has ? (T / fmaxf(c, 1.f)) : 0.f;                       // pre_avg_degree
    out[1] = has ? (2.f * T / (R * (R - 1.f) + 1e-4f)) : 0.f;       // pre_density
    out[2] = has ? R : 0.f;                                          // pre_avg_nodes
}

// ---------------------------------------------------------------------------
extern "C" void kernel_launch(void* const* d_in, const int* in_sizes, int n_in,
                              void* d_out, int out_size, void* d_ws, size_t ws_size,
                              hipStream_t stream) {
    (void)in_sizes; (void)n_in; (void)out_size; (void)ws_size;
    const float* adj  = (const float*)d_in[0];
    const float* Fda  = (const float*)d_in[1];
    const float* Qadj = (const float*)d_in[2];
    const float* Fq   = (const float*)d_in[3];
    const int*   cand = (const int*)d_in[4];
    // d_in[5] candidate_adj: unused by the reference
    const float* thr  = (const float*)d_in[6];
    const float* W1da = (const float*)d_in[7];
    const float* W1q  = (const float*)d_in[8];
    const float* W2da = (const float*)d_in[9];
    const float* W2q  = (const float*)d_in[10];

    float* out = (float*)d_out;
    float* o_end    = out;                           // [10000]
    float* o_attda2 = out + NDA;                     // [10000,256]
    float* o_attq2  = out + NDA + (size_t)NDA * D;   // [64,256]
    float* o_sc     = o_attq2 + NQ * D;              // [3] scalars

    char* w = (char*)d_ws;
    size_t off = 0;
    auto alloc = [&](size_t b) { size_t r = off; off += (b + 255) & ~(size_t)255; return r; };
    float* bufA = (float*)(w + alloc((size_t)NDA * D * 4));   // X1 -> Y2
    float* bufB = (float*)(w + alloc((size_t)NDA * D * 4));   // da1 -> H
    float* bufC = (float*)(w + alloc((size_t)NDA * D * 4));   // da2
    int* colsb   = (int*)(w + alloc((size_t)NDA * CAP * 4));
    int* rowcntb = (int*)(w + alloc((size_t)NDA * 4));
    float* mbuf  = (float*)(w + alloc((size_t)NDA * 4));
    float* Gb    = (float*)(w + alloc((size_t)D * D * 4));    // G (zeroed in stage0)
    char* zbase = w + alloc(256);                             // scalar accumulators
    float* cntb  = (float*)zbase;
    double* totb = (double*)(zbase + 8);
    double* trb  = (double*)(zbase + 16);
    float* xq   = (float*)(w + alloc((size_t)NQ * D * 4));    // Xq -> Zq
    float* q1b  = (float*)(w + alloc((size_t)NQ * D * 4));
    float* q2b  = (float*)(w + alloc((size_t)NQ * D * 4));
    float* hpart = (float*)(w + alloc((size_t)4 * NQ * D * 4));
    float* embb = (float*)(w + alloc((size_t)(D + 1) * 4));

    // Layer 1
    stage0_kernel<<<NB64 + 20 + NDA, 256, 0, stream>>>(adj, colsb, rowcntb,
                                                       Fda, W1da, bufA, Fq, W1q, xq, Gb);
    stage_sg_kernel<<<NDA + 4, 256, 0, stream>>>(colsb, rowcntb, bufA, bufB, (float*)nullptr,
                                                 Qadj, xq, q1b);                   // q1 | da1
    mergeA_kernel<<<256 + NB64, 256, 0, stream>>>(q1b, bufB, cand, hpart, W2da, bufA); // cross1 | Y2
    qfused_kernel<<<4, 256, 0, stream>>>(q1b, hpart, W2q, xq);                     // att_q1 -> Zq
    // Layer 2
    stage_sg_kernel<<<NDA + 4, 256, 0, stream>>>(colsb, rowcntb, bufA, bufC, o_attda2,
                                                 Qadj, xq, q2b);                   // q2 | da2
    cross_kernel<<<dim3(NQ, 4), 256, 0, stream>>>(q2b, bufC, cand, hpart);
    attq4_kernel<<<4, 256, 0, stream>>>(q2b, hpart, o_attq2, embb, cntb, totb, trb);
    // Scoring
    end_kernel<<<NDA / 4, 256, 0, stream>>>(o_attda2, embb, thr, o_end, mbuf, cntb);
    G_kernel<<<dim3(16, NDA / GCHUNK), 256, 0, stream>>>(o_attda2, mbuf, Gb);
    gemmH_kernel<<<dim3((NDA + 63) / 64, D / 64), 256, 0, stream>>>(o_attda2, Gb, bufB);
    final_kernel<<<NDA, 256, 0, stream>>>(colsb, rowcntb, mbuf, o_attda2, bufB, totb, trb);
    scalars_kernel<<<1, 1, 0, stream>>>(cntb, totb, trb, o_sc);
}